// Round 2
// baseline (1700.560 us; speedup 1.0000x reference)
//
#include <hip/hip_runtime.h>
#include <math.h>

#define PI_F 3.14159265358979323846f
#define NPIX 262144   // 512*512

// ---------------------------------------------------------------- dark channel
__global__ __launch_bounds__(256) void k_minc(const float* __restrict__ x, float* __restrict__ dm,
                                              int* __restrict__ gmax) {
    int p = blockIdx.x * 256 + threadIdx.x;
    if (p == 0) gmax[0] = 0;   // zero before k_mincol_max's atomics (stream-ordered)
    float m = fmaxf(x[p], fmaxf(x[p + NPIX], x[p + 2 * NPIX]));
    dm[p] = 1.0f - m;   // min over c of (1 - x_c)
}

__device__ __forceinline__ int refl512(int t) {
    if (t < 0) t = -t;
    if (t > 511) t = 1022 - t;
    return t;
}

__global__ __launch_bounds__(256) void k_minrow(const float* __restrict__ dm, float* __restrict__ tmp) {
    int p = blockIdx.x * 256 + threadIdx.x;
    int i = p >> 9, j = p & 511;
    float m = 1e30f;
    #pragma unroll
    for (int d = -7; d <= 7; d++) {
        int jj = refl512(j + d);
        m = fminf(m, dm[(i << 9) + jj]);
    }
    tmp[p] = m;
}

__global__ __launch_bounds__(256) void k_mincol_max(const float* __restrict__ tmp, float* __restrict__ dark,
                                                    int* __restrict__ gmax) {
    int p = blockIdx.x * 256 + threadIdx.x;
    int i = p >> 9, j = p & 511;
    float m = 1e30f;
    #pragma unroll
    for (int d = -7; d <= 7; d++) {
        int ii = refl512(i + d);
        m = fminf(m, tmp[(ii << 9) + j]);
    }
    dark[p] = m;
    __shared__ float red[256];
    int tid = threadIdx.x;
    red[tid] = m;
    __syncthreads();
    for (int s = 128; s > 0; s >>= 1) {
        if (tid < s) red[tid] = fmaxf(red[tid], red[tid + s]);
        __syncthreads();
    }
    if (tid == 0) atomicMax(gmax, __float_as_int(red[0]));  // values >= 0
}

// ---------------------------------------------------------------- ape = posenc + conv_cf1
__global__ __launch_bounds__(256) void k_ape(const float* __restrict__ x, const float* __restrict__ dark,
                                             const int* __restrict__ gmax,
                                             const float* __restrict__ w, const float* __restrict__ bias,
                                             float* __restrict__ ape) {
    __shared__ float dimt[32], ws[192], bs[64];
    int tid = threadIdx.x;
    if (tid < 32) dimt[tid] = powf(10000.f, (float)(2 * (tid >> 1)) / 32.f);
    if (tid < 192) ws[tid] = w[tid];
    if (tid < 64) bs[tid] = bias[tid];
    __syncthreads();
    int p = blockIdx.x * 256 + tid;
    int i = p >> 9, j = p & 511;
    const float scale = 2.f * PI_F;
    float inv511 = scale / (511.f + 1e-6f);
    float xe = (float)j * inv511;
    float ye = (float)i * inv511;
    float gm = __int_as_float(gmax[0]);
    float ze = dark[p] / (gm + 1e-6f) * scale;
    float x0 = x[p], x1 = x[p + NPIX], x2 = x[p + 2 * NPIX];
    #pragma unroll 1
    for (int o = 0; o < 64; o++) {
        float e;
        if (o < 16)      e = xe / dimt[o];
        else if (o < 32) e = ye / dimt[o - 16];
        else             e = ze / dimt[o - 32];
        float sn, cs;
        sincosf(e, &sn, &cs);
        float pos = ((o & 1) == 0) ? sn : cs;
        float conv = ws[o * 3] * x0 + ws[o * 3 + 1] * x1 + ws[o * 3 + 2] * x2 + bs[o];
        ape[(size_t)o * NPIX + p] = pos + conv;
    }
}

// ---------------------------------------------------------------- x_f = e2(e1(x))
__global__ __launch_bounds__(256) void k_ef(const float* __restrict__ x,
                                            const float* __restrict__ w1, const float* __restrict__ b1,
                                            const float* __restrict__ w2, const float* __restrict__ b2,
                                            float* __restrict__ out) {
    __shared__ float sw1[24], sb1[8], sw2[512], sb2[64];
    int tid = threadIdx.x;
    if (tid < 24) sw1[tid] = w1[tid];
    if (tid < 8)  sb1[tid] = b1[tid];
    if (tid < 64) sb2[tid] = b2[tid];
    if (tid < 256) { sw2[tid] = w2[tid]; sw2[tid + 256] = w2[tid + 256]; }
    __syncthreads();
    int p = blockIdx.x * 256 + tid;
    float x0 = x[p], x1 = x[p + NPIX], x2 = x[p + 2 * NPIX];
    float h[8];
    #pragma unroll
    for (int r = 0; r < 8; r++)
        h[r] = sw1[r * 3] * x0 + sw1[r * 3 + 1] * x1 + sw1[r * 3 + 2] * x2 + sb1[r];
    #pragma unroll 1
    for (int o = 0; o < 64; o++) {
        float acc = sb2[o];
        #pragma unroll
        for (int r = 0; r < 8; r++) acc += sw2[o * 8 + r] * h[r];
        out[(size_t)o * NPIX + p] = acc;
    }
}

// ---------------------------------------------------------------- generic GEMM  C[M,N] = A[M,K]*B[K,N]
// BMODE: 0 = direct B[K,N] (optional dual: rows >=64 from B2)
//        1 = space-to-depth gather: B(k,n) = src[c][2i+dy][2j+dx], k=c*4+dy*2+dx, n=i*Wo+j
//        2 = bilinear 2x upsample gather (jax.image.resize semantics)
// flags: 1 = lrelu. mul != null: multiply epilogue (mul may alias C elementwise).
template<int BMODE>
__global__ __launch_bounds__(256) void k_gemm(const float* __restrict__ A, int lda,
                                              const float* __restrict__ B, const float* __restrict__ B2,
                                              const float* __restrict__ bias,
                                              float* __restrict__ C,
                                              const float* __restrict__ mul,
                                              int N, int K,
                                              int wshift, int srcH, int srcW, int flags) {
    __shared__ float At[16][64];
    __shared__ float Bt[16][128];
    int tid = threadIdx.x;
    int tx = tid & 15, ty = tid >> 4;
    int n0 = blockIdx.x * 128;
    int m0 = blockIdx.y * 64;
    float acc[4][8] = {};
    for (int kb = 0; kb < K; kb += 16) {
        #pragma unroll
        for (int e = 0; e < 4; e++) {
            int i = e * 256 + tid;
            int mm = i & 63, kk = i >> 6;
            At[kk][mm] = A[(size_t)(m0 + mm) * lda + kb + kk];
        }
        #pragma unroll
        for (int e = 0; e < 8; e++) {
            int i = e * 256 + tid;
            int nn = i & 127, kk = i >> 7;
            int k = kb + kk, n = n0 + nn;
            float v;
            if (BMODE == 0) {
                const float* Bp = B;
                int kr = k;
                if (B2 && k >= 64) { Bp = B2; kr = k - 64; }
                v = Bp[(size_t)kr * N + n];
            } else if (BMODE == 1) {
                int c = k >> 2, dy = (k >> 1) & 1, dx = k & 1;
                int jj = n & ((1 << wshift) - 1), ii = n >> wshift;
                v = B[((size_t)c * srcH + (2 * ii + dy)) * srcW + (2 * jj + dx)];
            } else {
                int jj = n & ((1 << wshift) - 1), ii = n >> wshift;
                const float* p = B + (size_t)k * srcH * srcW;
                int ky = ii >> 1, ylo, yhi; float wyl, wyh;
                if ((ii & 1) == 0) { ylo = ky - 1; yhi = ky; wyl = .25f; wyh = .75f; if (ylo < 0) { ylo = 0; wyl = 0.f; wyh = 1.f; } }
                else               { ylo = ky; yhi = ky + 1; wyl = .75f; wyh = .25f; if (yhi > srcH - 1) { yhi = srcH - 1; wyh = 0.f; wyl = 1.f; } }
                int kx = jj >> 1, xlo, xhi; float wxl, wxh;
                if ((jj & 1) == 0) { xlo = kx - 1; xhi = kx; wxl = .25f; wxh = .75f; if (xlo < 0) { xlo = 0; wxl = 0.f; wxh = 1.f; } }
                else               { xlo = kx; xhi = kx + 1; wxl = .75f; wxh = .25f; if (xhi > srcW - 1) { xhi = srcW - 1; wxh = 0.f; wxl = 1.f; } }
                v = wyl * (wxl * p[(size_t)ylo * srcW + xlo] + wxh * p[(size_t)ylo * srcW + xhi]) +
                    wyh * (wxl * p[(size_t)yhi * srcW + xlo] + wxh * p[(size_t)yhi * srcW + xhi]);
            }
            Bt[kk][nn] = v;
        }
        __syncthreads();
        #pragma unroll
        for (int kk = 0; kk < 16; kk++) {
            float4 a  = *(const float4*)&At[kk][ty * 4];
            float4 b0 = *(const float4*)&Bt[kk][tx * 8];
            float4 b1 = *(const float4*)&Bt[kk][tx * 8 + 4];
            float av[4] = {a.x, a.y, a.z, a.w};
            float bv[8] = {b0.x, b0.y, b0.z, b0.w, b1.x, b1.y, b1.z, b1.w};
            #pragma unroll
            for (int r = 0; r < 4; r++)
                #pragma unroll
                for (int s = 0; s < 8; s++)
                    acc[r][s] += av[r] * bv[s];
        }
        __syncthreads();
    }
    #pragma unroll
    for (int r = 0; r < 4; r++) {
        int m = m0 + ty * 4 + r;
        float bs = bias ? bias[m] : 0.f;
        size_t base = (size_t)m * N + n0 + tx * 8;
        #pragma unroll
        for (int s = 0; s < 8; s++) {
            float v = acc[r][s] + bs;
            if (flags & 1) v = (v < 0.f) ? 0.1f * v : v;
            if (mul) v *= mul[base + s];
            C[base + s] = v;
        }
    }
}

// ---------------------------------------------------------------- DFT kernels (128-point)
__global__ __launch_bounds__(128) void k_r2c_row(const float* __restrict__ in, float2* __restrict__ out) {
    __shared__ float s[128];
    int b = blockIdx.x;   // c*128 + row
    int t = threadIdx.x;
    s[t] = in[(size_t)b * 128 + t];
    __syncthreads();
    if (t < 65) {
        float ang = -2.f * PI_F * (float)t / 128.f;
        float stepr, stepi;
        sincosf(ang, &stepi, &stepr);
        float re = 0.f, im = 0.f, cr = 1.f, ci = 0.f;
        for (int n = 0; n < 128; n++) {
            float v = s[n];
            re += v * cr;
            im += v * ci;
            float nr = cr * stepr - ci * stepi;
            ci = cr * stepi + ci * stepr;
            cr = nr;
        }
        out[(size_t)b * 65 + t] = make_float2(re, im);
    }
}

__global__ __launch_bounds__(128) void k_c2c_amp(const float2* __restrict__ in, float* __restrict__ amp) {
    __shared__ float2 s[128];
    int b = blockIdx.x;           // c*65 + k
    int c = b / 65, k = b - c * 65;
    int t = threadIdx.x;
    s[t] = in[((size_t)c * 128 + t) * 65 + k];
    __syncthreads();
    float ang = -2.f * PI_F * (float)t / 128.f;
    float stepr, stepi;
    sincosf(ang, &stepi, &stepr);
    float re = 0.f, im = 0.f, cr = 1.f, ci = 0.f;
    for (int m = 0; m < 128; m++) {
        float2 z = s[m];
        re += z.x * cr - z.y * ci;
        im += z.x * ci + z.y * cr;
        float nr = cr * stepr - ci * stepi;
        ci = cr * stepi + ci * stepr;
        cr = nr;
    }
    amp[((size_t)c * 128 + t) * 65 + k] = sqrtf(re * re + im * im);
}

__global__ __launch_bounds__(256) void k_buildz(const float* __restrict__ a2, float2* __restrict__ z) {
    size_t idx = (size_t)blockIdx.x * 256 + threadIdx.x;
    float a = a2[idx];
    float sn, cs;
    sincosf(a, &sn, &cs);
    z[idx] = make_float2(a * cs, a * sn);
}

__global__ __launch_bounds__(128) void k_c2c_inv(const float2* __restrict__ in, float2* __restrict__ out) {
    __shared__ float2 s[128];
    int b = blockIdx.x;           // c*65 + k
    int c = b / 65, k = b - c * 65;
    int t = threadIdx.x;
    s[t] = in[((size_t)c * 128 + t) * 65 + k];
    __syncthreads();
    float ang = 2.f * PI_F * (float)t / 128.f;
    float stepr, stepi;
    sincosf(ang, &stepi, &stepr);
    float re = 0.f, im = 0.f, cr = 1.f, ci = 0.f;
    for (int m = 0; m < 128; m++) {
        float2 z = s[m];
        re += z.x * cr - z.y * ci;
        im += z.x * ci + z.y * cr;
        float nr = cr * stepr - ci * stepi;
        ci = cr * stepi + ci * stepr;
        cr = nr;
    }
    out[((size_t)c * 128 + t) * 65 + k] = make_float2(re * (1.f / 128.f), im * (1.f / 128.f));
}

__global__ __launch_bounds__(128) void k_c2r_row(const float2* __restrict__ in, float* __restrict__ out) {
    __shared__ float2 s[65];
    int b = blockIdx.x;   // c*128 + row
    int t = threadIdx.x;
    if (t < 65) s[t] = in[(size_t)b * 65 + t];
    __syncthreads();
    float ang = 2.f * PI_F * (float)t / 128.f;
    float stepr, stepi;
    sincosf(ang, &stepi, &stepr);
    float cr = stepr, ci = stepi;   // k = 1
    float acc = 0.f;
    for (int k = 1; k < 64; k++) {
        float2 z = s[k];
        acc += z.x * cr - z.y * ci;
        float nr = cr * stepr - ci * stepi;
        ci = cr * stepi + ci * stepr;
        cr = nr;
    }
    acc += 0.5f * s[0].x;
    acc += ((t & 1) ? -0.5f : 0.5f) * s[64].x;
    out[(size_t)b * 128 + t] = acc * (2.f / 128.f);
}

// ---------------------------------------------------------------- cf3 + residual
__global__ __launch_bounds__(256) void k_cf3_res(const float* __restrict__ c64, const float* __restrict__ w,
                                                 const float* __restrict__ bias, const float* __restrict__ x,
                                                 float* __restrict__ out) {
    __shared__ float ws[192], bs[3];
    int tid = threadIdx.x;
    if (tid < 192) ws[tid] = w[tid];
    if (tid < 3) bs[tid] = bias[tid];
    __syncthreads();
    int p = blockIdx.x * 256 + tid;
    float a0 = bs[0], a1 = bs[1], a2 = bs[2];
    #pragma unroll 4
    for (int k = 0; k < 64; k++) {
        float v = c64[(size_t)k * NPIX + p];
        a0 += ws[k] * v;
        a1 += ws[64 + k] * v;
        a2 += ws[128 + k] * v;
    }
    out[p]            = a0 + x[p];
    out[NPIX + p]     = a1 + x[NPIX + p];
    out[2 * NPIX + p] = a2 + x[2 * NPIX + p];
}

// ================================================================ launcher
extern "C" void kernel_launch(void* const* d_in, const int* in_sizes, int n_in,
                              void* d_out, int out_size, void* d_ws, size_t ws_size,
                              hipStream_t stream) {
    const float* x      = (const float*)d_in[0];
    const float* w_cf1  = (const float*)d_in[1];  const float* b_cf1 = (const float*)d_in[2];
    const float* w_e1   = (const float*)d_in[3];  const float* b_e1  = (const float*)d_in[4];
    const float* w_e2   = (const float*)d_in[5];  const float* b_e2  = (const float*)d_in[6];
    const float* w_d1   = (const float*)d_in[7];  const float* b_d1  = (const float*)d_in[8];
    const float* w_d2   = (const float*)d_in[9];  const float* b_d2  = (const float*)d_in[10];
    // 11..14: pha branch is dead code in the reference (its output is never used)
    const float* w_amp1 = (const float*)d_in[15]; const float* b_amp1 = (const float*)d_in[16];
    const float* w_amp2 = (const float*)d_in[17]; const float* b_amp2 = (const float*)d_in[18];
    const float* w_sp1  = (const float*)d_in[19]; const float* b_sp1  = (const float*)d_in[20];
    const float* w_sp2  = (const float*)d_in[21]; const float* b_sp2  = (const float*)d_in[22];
    const float* w_u1   = (const float*)d_in[23]; const float* b_u1   = (const float*)d_in[24];
    const float* w_u2   = (const float*)d_in[25]; const float* b_u2   = (const float*)d_in[26];
    const float* w_u3   = (const float*)d_in[27]; const float* b_u3   = (const float*)d_in[28];
    const float* w_u4   = (const float*)d_in[29]; const float* b_u4   = (const float*)d_in[30];
    const float* w_cf2  = (const float*)d_in[31]; const float* b_cf2  = (const float*)d_in[32];
    const float* w_cf3  = (const float*)d_in[33]; const float* b_cf3  = (const float*)d_in[34];
    float* out = (float*)d_out;

    // ---- workspace layout (MiB offsets), peak 214 MiB ----
    char* ws = (char*)d_ws;
    constexpr size_t MiB = 1ull << 20;
    float*  dark   = (float*)(ws + 0 * MiB);     // 1
    float*  tmp    = (float*)(ws + 1 * MiB);     // 1
    int*    gmax   = (int*)  (ws + 2 * MiB);
    float*  slotA  = (float*)(ws + 3 * MiB);     // 64: xf -> ape/spat (in-place)
    float*  slotB  = (float*)(ws + 67 * MiB);    // 64: xd1 (32) -> fbig (64)
    float*  slotC  = (float*)(ws + 131 * MiB);   // 32: u1out -> u3out ; later start of c64
    char*   D      = ws + 163 * MiB;             // 35: fft arena / fsmall / s1,s2
    float*  xd2    = (float*)(ws + 198 * MiB);   // 16

    float*  xf     = slotA;
    float*  apebuf = slotA;       // written after d1 consumed xf; u4 multiplies in place
    float*  xd1    = slotB;       // 32 MiB
    float*  fbig   = slotB;       // 64 MiB, after xd1 dead
    float*  u1out  = slotC;
    float*  u3out  = slotC;
    float*  c64    = slotC;       // 64 MiB spanning [131,195) — C+D dead by then
    float2* rowfft = (float2*)(D + 0 * MiB);     // 16.25
    float*  ampb   = (float*) (D + 17 * MiB);    // 8.125
    float*  A1     = (float*) (D + 0 * MiB);     // 8.125
    float*  A2     = (float*) (D + 26 * MiB);    // 8.125 (ends 197.125 < 198)
    float2* Zb     = (float2*)(D + 0 * MiB);     // 16.25
    float2* ifftb  = (float2*)(D + 17 * MiB);    // 16.25 (ends 196.25 < 198)
    float*  fsmall = (float*) (D + 0 * MiB);     // 16
    float*  s1     = (float*) (D + 0 * MiB);     // 16
    float*  s2     = (float*) (D + 17 * MiB);    // 16

    // 1) dark channel + global max
    k_minc<<<1024, 256, 0, stream>>>(x, dark, gmax);
    k_minrow<<<1024, 256, 0, stream>>>(dark, tmp);
    k_mincol_max<<<1024, 256, 0, stream>>>(tmp, dark, gmax);

    // 2) x_f = e2(e1(x))
    k_ef<<<1024, 256, 0, stream>>>(x, w_e1, b_e1, w_e2, b_e2, xf);

    // 3) d1: fused s2d GEMM  (M=128,K=256,N=65536), src xf 64ch@512x512 -> 256x256 grid
    k_gemm<1><<<dim3(512, 2), 256, 0, stream>>>(w_d1, 256, xf, nullptr, b_d1, xd1, nullptr,
                                                65536, 256, 8, 512, 512, 0);

    // 4) ape (into slotA; xf now dead)
    k_ape<<<1024, 256, 0, stream>>>(x, dark, gmax, w_cf1, b_cf1, apebuf);

    // 5) d2: fused s2d GEMM (M=256,K=512,N=16384), src xd1 128ch@256x256 -> 128x128
    k_gemm<1><<<dim3(128, 4), 256, 0, stream>>>(w_d2, 512, xd1, nullptr, b_d2, xd2, nullptr,
                                                16384, 512, 7, 256, 256, 0);

    // 6) forward rfft2 -> amp
    k_r2c_row<<<32768, 128, 0, stream>>>(xd2, rowfft);
    k_c2c_amp<<<16640, 128, 0, stream>>>(rowfft, ampb);

    // 7) amp MLP (M=256,K=256,N=8320)
    k_gemm<0><<<dim3(65, 4), 256, 0, stream>>>(w_amp1, 256, ampb, nullptr, b_amp1, A1, nullptr,
                                               8320, 256, 0, 0, 0, 1);
    k_gemm<0><<<dim3(65, 4), 256, 0, stream>>>(w_amp2, 256, A1, nullptr, b_amp2, A2, nullptr,
                                               8320, 256, 0, 0, 0, 0);

    // 8) z = A*(cosA,sinA); irfft2
    k_buildz<<<8320, 256, 0, stream>>>(A2, Zb);
    k_c2c_inv<<<16640, 128, 0, stream>>>(Zb, ifftb);
    k_c2r_row<<<32768, 128, 0, stream>>>(ifftb, fsmall);

    // 9) four path: fused resize GEMMs
    k_gemm<2><<<dim3(512, 2), 256, 0, stream>>>(w_u1, 256, fsmall, nullptr, b_u1, u1out, nullptr,
                                                65536, 256, 8, 128, 128, 0);
    k_gemm<2><<<dim3(2048, 1), 256, 0, stream>>>(w_u2, 128, u1out, nullptr, b_u2, fbig, nullptr,
                                                 262144, 128, 9, 256, 256, 0);

    // 10) spat path
    k_gemm<0><<<dim3(128, 4), 256, 0, stream>>>(w_sp1, 256, xd2, nullptr, b_sp1, s1, nullptr,
                                                16384, 256, 0, 0, 0, 1);
    k_gemm<0><<<dim3(128, 4), 256, 0, stream>>>(w_sp2, 256, s1, nullptr, b_sp2, s2, nullptr,
                                                16384, 256, 0, 0, 0, 0);
    k_gemm<2><<<dim3(512, 2), 256, 0, stream>>>(w_u3, 256, s2, nullptr, b_u3, u3out, nullptr,
                                                65536, 256, 8, 128, 128, 0);
    // u4 multiplies ape in place: C == mul == apebuf (element-wise read-then-write, same thread)
    k_gemm<2><<<dim3(2048, 1), 256, 0, stream>>>(w_u4, 128, u3out, nullptr, b_u4, apebuf, apebuf,
                                                 262144, 128, 9, 256, 256, 0);

    // 11) cf2: single dual-B GEMM over concat [fbig; spat] (M=64,K=128,N=262144)
    k_gemm<0><<<dim3(2048, 1), 256, 0, stream>>>(w_cf2, 128, fbig, apebuf, b_cf2, c64, nullptr,
                                                 262144, 128, 0, 0, 0, 0);

    // 12) cf3 + residual
    k_cf3_res<<<1024, 256, 0, stream>>>(c64, w_cf3, b_cf3, x, out);
}

// Round 3
// 1296.584 us; speedup vs baseline: 1.3116x; 1.3116x over previous
//
#include <hip/hip_runtime.h>
#include <math.h>

#define PI_F 3.14159265358979323846f
#define NPIX 262144   // 512*512

// ---------------------------------------------------------------- dark channel
__global__ __launch_bounds__(256) void k_minc(const float* __restrict__ x, float* __restrict__ dm,
                                              int* __restrict__ gmax) {
    int p = blockIdx.x * 256 + threadIdx.x;
    if (p == 0) gmax[0] = 0;   // zero before k_mincol_max's atomics (stream-ordered)
    float m = fmaxf(x[p], fmaxf(x[p + NPIX], x[p + 2 * NPIX]));
    dm[p] = 1.0f - m;
}

__device__ __forceinline__ int refl512(int t) {
    if (t < 0) t = -t;
    if (t > 511) t = 1022 - t;
    return t;
}

__global__ __launch_bounds__(256) void k_minrow(const float* __restrict__ dm, float* __restrict__ tmp) {
    int p = blockIdx.x * 256 + threadIdx.x;
    int i = p >> 9, j = p & 511;
    float m = 1e30f;
    #pragma unroll
    for (int d = -7; d <= 7; d++) m = fminf(m, dm[(i << 9) + refl512(j + d)]);
    tmp[p] = m;
}

__global__ __launch_bounds__(256) void k_mincol_max(const float* __restrict__ tmp, float* __restrict__ dark,
                                                    int* __restrict__ gmax) {
    int p = blockIdx.x * 256 + threadIdx.x;
    int i = p >> 9, j = p & 511;
    float m = 1e30f;
    #pragma unroll
    for (int d = -7; d <= 7; d++) m = fminf(m, tmp[(refl512(i + d) << 9) + j]);
    dark[p] = m;
    __shared__ float red[256];
    int tid = threadIdx.x;
    red[tid] = m;
    __syncthreads();
    for (int s = 128; s > 0; s >>= 1) {
        if (tid < s) red[tid] = fmaxf(red[tid], red[tid + s]);
        __syncthreads();
    }
    if (tid == 0) atomicMax(gmax, __float_as_int(red[0]));
}

// ---------------------------------------------------------------- Wc = w_cf3 @ w_cf2 (3x128), bc = w_cf3@b_cf2+b_cf3
__global__ __launch_bounds__(128) void k_wc(const float* __restrict__ w2, const float* __restrict__ b2,
                                            const float* __restrict__ w3, const float* __restrict__ b3,
                                            float* __restrict__ Wc, float* __restrict__ bc) {
    int j = threadIdx.x;  // 0..127
    for (int r = 0; r < 3; r++) {
        float s = 0.f;
        for (int o = 0; o < 64; o++) s += w3[r * 64 + o] * w2[o * 128 + j];
        Wc[r * 128 + j] = s;
    }
    if (j < 3) {
        float s = b3[j];
        for (int o = 0; o < 64; o++) s += w3[j * 64 + o] * b2[o];
        bc[j] = s;
    }
}

// ---------------------------------------------------------------- x_f = e2(e1(x))
__global__ __launch_bounds__(256) void k_ef(const float* __restrict__ x,
                                            const float* __restrict__ w1, const float* __restrict__ b1,
                                            const float* __restrict__ w2, const float* __restrict__ b2,
                                            float* __restrict__ out) {
    __shared__ float sw1[24], sb1[8], sw2[512], sb2[64];
    int tid = threadIdx.x;
    if (tid < 24) sw1[tid] = w1[tid];
    if (tid < 8)  sb1[tid] = b1[tid];
    if (tid < 64) sb2[tid] = b2[tid];
    if (tid < 256) { sw2[tid] = w2[tid]; sw2[tid + 256] = w2[tid + 256]; }
    __syncthreads();
    int p = blockIdx.x * 256 + tid;
    float x0 = x[p], x1 = x[p + NPIX], x2 = x[p + 2 * NPIX];
    float h[8];
    #pragma unroll
    for (int r = 0; r < 8; r++)
        h[r] = sw1[r * 3] * x0 + sw1[r * 3 + 1] * x1 + sw1[r * 3 + 2] * x2 + sb1[r];
    #pragma unroll 1
    for (int o = 0; o < 64; o++) {
        float acc = sb2[o];
        #pragma unroll
        for (int r = 0; r < 8; r++) acc += sw2[o * 8 + r] * h[r];
        out[(size_t)o * NPIX + p] = acc;
    }
}

// ---------------------------------------------------------------- GEMM  C[M,N] = A[M,K]*B[K,N]
// tile 64(M) x 256(N), micro 8x8, K-chunk 8, 256 threads.
// BMODE: 0 direct B[K,N]; 1 space-to-depth gather; 2 bilinear-2x-upsample gather.
// flags: 1 = lrelu
template<int BMODE>
__global__ __launch_bounds__(256) void k_gemm(const float* __restrict__ A, int lda,
                                              const float* __restrict__ B,
                                              const float* __restrict__ bias,
                                              float* __restrict__ C,
                                              int N, int K,
                                              int wshift, int srcH, int srcW, int flags) {
    __shared__ float As[8][64];
    __shared__ float Bs[8][256];
    int tid = threadIdx.x;
    int tx = tid & 31, ty = tid >> 5;
    int n0 = blockIdx.x * 256;
    int m0 = blockIdx.y * 64;
    float acc[8][8] = {};
    for (int kb = 0; kb < K; kb += 8) {
        #pragma unroll
        for (int e = 0; e < 2; e++) {
            int i = e * 256 + tid;
            int mm = i & 63, kk = i >> 6;
            As[kk][mm] = A[(size_t)(m0 + mm) * lda + kb + kk];
        }
        #pragma unroll
        for (int e = 0; e < 8; e++) {
            int i = e * 256 + tid;
            int nn = i & 255, kk = i >> 8;
            int k = kb + kk, n = n0 + nn;
            float v = 0.f;
            if (BMODE == 0) {
                if (n < N) v = B[(size_t)k * N + n];
            } else if (BMODE == 1) {
                int c = k >> 2, dy = (k >> 1) & 1, dx = k & 1;
                int jj = n & ((1 << wshift) - 1), ii = n >> wshift;
                v = B[((size_t)c * srcH + (2 * ii + dy)) * srcW + (2 * jj + dx)];
            } else {
                int jj = n & ((1 << wshift) - 1), ii = n >> wshift;
                const float* p = B + (size_t)k * srcH * srcW;
                int ky = ii >> 1, ylo, yhi; float wyl, wyh;
                if ((ii & 1) == 0) { ylo = ky - 1; yhi = ky; wyl = .25f; wyh = .75f; if (ylo < 0) { ylo = 0; wyl = 0.f; wyh = 1.f; } }
                else               { ylo = ky; yhi = ky + 1; wyl = .75f; wyh = .25f; if (yhi > srcH - 1) { yhi = srcH - 1; wyh = 0.f; wyl = 1.f; } }
                int kx = jj >> 1, xlo, xhi; float wxl, wxh;
                if ((jj & 1) == 0) { xlo = kx - 1; xhi = kx; wxl = .25f; wxh = .75f; if (xlo < 0) { xlo = 0; wxl = 0.f; wxh = 1.f; } }
                else               { xlo = kx; xhi = kx + 1; wxl = .75f; wxh = .25f; if (xhi > srcW - 1) { xhi = srcW - 1; wxh = 0.f; wxl = 1.f; } }
                v = wyl * (wxl * p[(size_t)ylo * srcW + xlo] + wxh * p[(size_t)ylo * srcW + xhi]) +
                    wyh * (wxl * p[(size_t)yhi * srcW + xlo] + wxh * p[(size_t)yhi * srcW + xhi]);
            }
            Bs[kk][nn] = v;
        }
        __syncthreads();
        #pragma unroll
        for (int kk = 0; kk < 8; kk++) {
            float4 A0 = *(const float4*)&As[kk][ty * 8];
            float4 A1 = *(const float4*)&As[kk][ty * 8 + 4];
            float4 B0 = *(const float4*)&Bs[kk][tx * 4];
            float4 B1 = *(const float4*)&Bs[kk][128 + tx * 4];
            float av[8] = {A0.x, A0.y, A0.z, A0.w, A1.x, A1.y, A1.z, A1.w};
            float bv[8] = {B0.x, B0.y, B0.z, B0.w, B1.x, B1.y, B1.z, B1.w};
            #pragma unroll
            for (int r = 0; r < 8; r++)
                #pragma unroll
                for (int s = 0; s < 8; s++)
                    acc[r][s] += av[r] * bv[s];
        }
        __syncthreads();
    }
    int n1 = n0 + tx * 4, n2 = n0 + 128 + tx * 4;
    #pragma unroll
    for (int r = 0; r < 8; r++) {
        int m = m0 + ty * 8 + r;
        float bs = bias ? bias[m] : 0.f;
        float o[8];
        #pragma unroll
        for (int s = 0; s < 8; s++) {
            float v = acc[r][s] + bs;
            if (flags & 1) v = (v < 0.f) ? 0.1f * v : v;
            o[s] = v;
        }
        size_t rowb = (size_t)m * N;
        if (n1 < N) *(float4*)&C[rowb + n1] = make_float4(o[0], o[1], o[2], o[3]);
        if (n2 < N) *(float4*)&C[rowb + n2] = make_float4(o[4], o[5], o[6], o[7]);
    }
}

// ---------------------------------------------------------------- DFT kernels (128-point)
__global__ __launch_bounds__(128) void k_r2c_row(const float* __restrict__ in, float2* __restrict__ out) {
    __shared__ float s[128];
    int b = blockIdx.x;   // c*128 + row
    int t = threadIdx.x;
    s[t] = in[(size_t)b * 128 + t];
    __syncthreads();
    if (t < 65) {
        float ang = -2.f * PI_F * (float)t / 128.f;
        float stepr, stepi;
        sincosf(ang, &stepi, &stepr);
        float re = 0.f, im = 0.f, cr = 1.f, ci = 0.f;
        for (int n = 0; n < 128; n++) {
            float v = s[n];
            re += v * cr;
            im += v * ci;
            float nr = cr * stepr - ci * stepi;
            ci = cr * stepi + ci * stepr;
            cr = nr;
        }
        out[(size_t)b * 65 + t] = make_float2(re, im);
    }
}

__global__ __launch_bounds__(128) void k_c2c_amp(const float2* __restrict__ in, float* __restrict__ amp) {
    __shared__ float2 s[128];
    int b = blockIdx.x;           // c*65 + k
    int c = b / 65, k = b - c * 65;
    int t = threadIdx.x;
    s[t] = in[((size_t)c * 128 + t) * 65 + k];
    __syncthreads();
    float ang = -2.f * PI_F * (float)t / 128.f;
    float stepr, stepi;
    sincosf(ang, &stepi, &stepr);
    float re = 0.f, im = 0.f, cr = 1.f, ci = 0.f;
    for (int m = 0; m < 128; m++) {
        float2 z = s[m];
        re += z.x * cr - z.y * ci;
        im += z.x * ci + z.y * cr;
        float nr = cr * stepr - ci * stepi;
        ci = cr * stepi + ci * stepr;
        cr = nr;
    }
    amp[((size_t)c * 128 + t) * 65 + k] = sqrtf(re * re + im * im);
}

// inverse col FFT, z = a*(cos a + i sin a) built in-register from amp2
__global__ __launch_bounds__(128) void k_c2c_inv(const float* __restrict__ amp2, float2* __restrict__ out) {
    __shared__ float2 s[128];
    int b = blockIdx.x;           // c*65 + k
    int c = b / 65, k = b - c * 65;
    int t = threadIdx.x;
    float a = amp2[((size_t)c * 128 + t) * 65 + k];
    float zs, zc;
    sincosf(a, &zs, &zc);
    s[t] = make_float2(a * zc, a * zs);
    __syncthreads();
    float ang = 2.f * PI_F * (float)t / 128.f;
    float stepr, stepi;
    sincosf(ang, &stepi, &stepr);
    float re = 0.f, im = 0.f, cr = 1.f, ci = 0.f;
    for (int m = 0; m < 128; m++) {
        float2 z = s[m];
        re += z.x * cr - z.y * ci;
        im += z.x * ci + z.y * cr;
        float nr = cr * stepr - ci * stepi;
        ci = cr * stepi + ci * stepr;
        cr = nr;
    }
    out[((size_t)c * 128 + t) * 65 + k] = make_float2(re * (1.f / 128.f), im * (1.f / 128.f));
}

__global__ __launch_bounds__(128) void k_c2r_row(const float2* __restrict__ in, float* __restrict__ out) {
    __shared__ float2 s[65];
    int b = blockIdx.x;   // c*128 + row
    int t = threadIdx.x;
    if (t < 65) s[t] = in[(size_t)b * 65 + t];
    __syncthreads();
    float ang = 2.f * PI_F * (float)t / 128.f;
    float stepr, stepi;
    sincosf(ang, &stepi, &stepr);
    float cr = stepr, ci = stepi;   // k = 1
    float acc = 0.f;
    for (int k = 1; k < 64; k++) {
        float2 z = s[k];
        acc += z.x * cr - z.y * ci;
        float nr = cr * stepr - ci * stepi;
        ci = cr * stepi + ci * stepr;
        cr = nr;
    }
    acc += 0.5f * s[0].x;
    acc += ((t & 1) ? -0.5f : 0.5f) * s[64].x;
    out[(size_t)b * 128 + t] = acc * (2.f / 128.f);
}

// ---------------------------------------------------------------- h3 = Wc[:, :64] @ g2   (3ch @256^2)
__global__ __launch_bounds__(256) void k_h3(const float* __restrict__ g2, const float* __restrict__ Wc,
                                            float* __restrict__ h3) {
    __shared__ float wa[192];
    int tid = threadIdx.x;
    if (tid < 192) { int r = tid >> 6, c = tid & 63; wa[tid] = Wc[r * 128 + c]; }
    __syncthreads();
    int q = blockIdx.x * 256 + tid;  // 65536
    float a0 = 0.f, a1 = 0.f, a2 = 0.f;
    #pragma unroll 4
    for (int c = 0; c < 64; c++) {
        float v = g2[(size_t)c * 65536 + q];
        a0 += wa[c] * v;
        a1 += wa[64 + c] * v;
        a2 += wa[128 + c] * v;
    }
    h3[q] = a0; h3[65536 + q] = a1; h3[131072 + q] = a2;
}

// ---------------------------------------------------------------- final fused stage @512^2
// out = resize(h3) + Wc[:,64:] @ (resize(g4) * ape) + bc + x ;  ape = posenc + cf1(x)
__global__ __launch_bounds__(256) void k_final(const float* __restrict__ x,
                                               const float* __restrict__ dark, const int* __restrict__ gmax,
                                               const float* __restrict__ wcf1, const float* __restrict__ bcf1,
                                               const float* __restrict__ Wc, const float* __restrict__ bc,
                                               const float* __restrict__ g4, const float* __restrict__ h3,
                                               float* __restrict__ out) {
    __shared__ float dimt[32], w1[192], b1[64], wb[192], bcs[3];
    int tid = threadIdx.x;
    if (tid < 32) dimt[tid] = powf(10000.f, (float)(2 * (tid >> 1)) / 32.f);
    if (tid < 192) w1[tid] = wcf1[tid];
    if (tid < 64) b1[tid] = bcf1[tid];
    if (tid < 192) { int r = tid / 64, c = tid - (tid / 64) * 64; wb[tid] = Wc[r * 128 + 64 + c]; }
    if (tid < 3) bcs[tid] = bc[tid];
    __syncthreads();
    int p = blockIdx.x * 256 + tid;
    int i = p >> 9, j = p & 511;
    const float scale = 2.f * PI_F;
    float inv511 = scale / (511.f + 1e-6f);
    float xe = (float)j * inv511, ye = (float)i * inv511;
    float gm = __int_as_float(gmax[0]);
    float ze = dark[p] / (gm + 1e-6f) * scale;
    float x0 = x[p], x1 = x[p + NPIX], x2 = x[p + 2 * NPIX];

    // bilinear taps 512 -> src 256
    int ky = i >> 1, ylo, yhi; float wyl, wyh;
    if ((i & 1) == 0) { ylo = ky - 1; yhi = ky; wyl = .25f; wyh = .75f; if (ylo < 0) { ylo = 0; wyl = 0.f; wyh = 1.f; } }
    else              { ylo = ky; yhi = ky + 1; wyl = .75f; wyh = .25f; if (yhi > 255) { yhi = 255; wyh = 0.f; wyl = 1.f; } }
    int kx = j >> 1, xlo, xhi; float wxl, wxh;
    if ((j & 1) == 0) { xlo = kx - 1; xhi = kx; wxl = .25f; wxh = .75f; if (xlo < 0) { xlo = 0; wxl = 0.f; wxh = 1.f; } }
    else              { xlo = kx; xhi = kx + 1; wxl = .75f; wxh = .25f; if (xhi > 255) { xhi = 255; wxh = 0.f; wxl = 1.f; } }
    int s00 = ylo * 256 + xlo, s01 = ylo * 256 + xhi, s10 = yhi * 256 + xlo, s11 = yhi * 256 + xhi;
    float w00 = wyl * wxl, w01 = wyl * wxh, w10 = wyh * wxl, w11 = wyh * wxh;

    float a0 = 0.f, a1 = 0.f, a2 = 0.f;
    #pragma unroll 1
    for (int c = 0; c < 64; c++) {
        float e = (c < 16) ? xe / dimt[c] : (c < 32) ? ye / dimt[c - 16] : ze / dimt[c - 32];
        float sn, cs;
        __sincosf(e, &sn, &cs);
        float pos = ((c & 1) == 0) ? sn : cs;
        float ape = pos + w1[c * 3] * x0 + w1[c * 3 + 1] * x1 + w1[c * 3 + 2] * x2 + b1[c];
        const float* gp = g4 + (size_t)c * 65536;
        float gv = w00 * gp[s00] + w01 * gp[s01] + w10 * gp[s10] + w11 * gp[s11];
        float s = gv * ape;
        a0 += wb[c] * s; a1 += wb[64 + c] * s; a2 += wb[128 + c] * s;
    }
    float f0 = w00 * h3[s00] + w01 * h3[s01] + w10 * h3[s10] + w11 * h3[s11];
    const float* h1 = h3 + 65536;
    float f1 = w00 * h1[s00] + w01 * h1[s01] + w10 * h1[s10] + w11 * h1[s11];
    const float* h2 = h3 + 131072;
    float f2 = w00 * h2[s00] + w01 * h2[s01] + w10 * h2[s10] + w11 * h2[s11];
    out[p]            = a0 + f0 + bcs[0] + x0;
    out[NPIX + p]     = a1 + f1 + bcs[1] + x1;
    out[2 * NPIX + p] = a2 + f2 + bcs[2] + x2;
}

// ================================================================ launcher
extern "C" void kernel_launch(void* const* d_in, const int* in_sizes, int n_in,
                              void* d_out, int out_size, void* d_ws, size_t ws_size,
                              hipStream_t stream) {
    const float* x      = (const float*)d_in[0];
    const float* w_cf1  = (const float*)d_in[1];  const float* b_cf1 = (const float*)d_in[2];
    const float* w_e1   = (const float*)d_in[3];  const float* b_e1  = (const float*)d_in[4];
    const float* w_e2   = (const float*)d_in[5];  const float* b_e2  = (const float*)d_in[6];
    const float* w_d1   = (const float*)d_in[7];  const float* b_d1  = (const float*)d_in[8];
    const float* w_d2   = (const float*)d_in[9];  const float* b_d2  = (const float*)d_in[10];
    // 11..14: pha branch is dead code in the reference (its output is never used)
    const float* w_amp1 = (const float*)d_in[15]; const float* b_amp1 = (const float*)d_in[16];
    const float* w_amp2 = (const float*)d_in[17]; const float* b_amp2 = (const float*)d_in[18];
    const float* w_sp1  = (const float*)d_in[19]; const float* b_sp1  = (const float*)d_in[20];
    const float* w_sp2  = (const float*)d_in[21]; const float* b_sp2  = (const float*)d_in[22];
    const float* w_u1   = (const float*)d_in[23]; const float* b_u1   = (const float*)d_in[24];
    const float* w_u2   = (const float*)d_in[25]; const float* b_u2   = (const float*)d_in[26];
    const float* w_u3   = (const float*)d_in[27]; const float* b_u3   = (const float*)d_in[28];
    const float* w_u4   = (const float*)d_in[29]; const float* b_u4   = (const float*)d_in[30];
    const float* w_cf2  = (const float*)d_in[31]; const float* b_cf2  = (const float*)d_in[32];
    const float* w_cf3  = (const float*)d_in[33]; const float* b_cf3  = (const float*)d_in[34];
    float* out = (float*)d_out;

    // ---- workspace layout (MiB offsets), peak ~150 MiB ----
    char* ws = (char*)d_ws;
    constexpr size_t MiB = 1ull << 20;
    float*  dark   = (float*)(ws + 0 * MiB);
    float*  tmp    = (float*)(ws + 1 * MiB);
    int*    gmax   = (int*)  (ws + 2 * MiB);
    float*  Wc     = (float*)(ws + 2 * MiB + 256);       // 3x128
    float*  bc     = (float*)(ws + 2 * MiB + 256 + 1536);// 3
    float*  xf     = (float*)(ws + 3 * MiB);     // 64 MiB [3,67)
    float*  xd1    = (float*)(ws + 67 * MiB);    // 32 MiB [67,99)
    float*  xd2    = (float*)(ws + 99 * MiB);    // 16 MiB [99,115) (live until sp1)
    float2* rowfft = (float2*)(ws + 115 * MiB);  // 16.25 [115,131.25)
    float*  ampb   = (float*)(ws + 132 * MiB);   // 8.125 [132,140.125)
    float*  A1     = (float*)(ws + 115 * MiB);   // 8.125 (rowfft dead)
    float*  A2     = (float*)(ws + 124 * MiB);   // 8.125 [124,132.125)
    float2* ifftb  = (float2*)(ws + 133 * MiB);  // 16.25 [133,149.25)
    float*  fsmall = (float*)(ws + 115 * MiB);   // 16 [115,131) (A1 dead)
    float*  g1out  = (float*)(ws + 3 * MiB);     // 8  [3,11)  (xf dead after d1)
    float*  g2out  = (float*)(ws + 11 * MiB);    // 16 [11,27)
    float*  h3     = (float*)(ws + 27 * MiB);    // 0.75
    float*  s1     = (float*)(ws + 31 * MiB);    // 16 [31,47)
    float*  s2     = (float*)(ws + 47 * MiB);    // 16 [47,63)
    float*  g3out  = (float*)(ws + 63 * MiB);    // 8  [63,71) (xd1 dead)
    float*  g4out  = (float*)(ws + 71 * MiB);    // 16 [71,87)

    // 1) dark channel + global max + composed cf weights
    k_minc<<<1024, 256, 0, stream>>>(x, dark, gmax);
    k_minrow<<<1024, 256, 0, stream>>>(dark, tmp);
    k_mincol_max<<<1024, 256, 0, stream>>>(tmp, dark, gmax);
    k_wc<<<1, 128, 0, stream>>>(w_cf2, b_cf2, w_cf3, b_cf3, Wc, bc);

    // 2) x_f = e2(e1(x))
    k_ef<<<1024, 256, 0, stream>>>(x, w_e1, b_e1, w_e2, b_e2, xf);

    // 3) d1: fused s2d GEMM (M=128,K=256,N=65536), src xf 64ch@512^2
    k_gemm<1><<<dim3(256, 2), 256, 0, stream>>>(w_d1, 256, xf, b_d1, xd1, 65536, 256, 8, 512, 512, 0);

    // 4) d2: fused s2d GEMM (M=256,K=512,N=16384), src xd1 128ch@256^2
    k_gemm<1><<<dim3(64, 4), 256, 0, stream>>>(w_d2, 512, xd1, b_d2, xd2, 16384, 512, 7, 256, 256, 0);

    // 5) forward rfft2 -> amp
    k_r2c_row<<<32768, 128, 0, stream>>>(xd2, rowfft);
    k_c2c_amp<<<16640, 128, 0, stream>>>(rowfft, ampb);

    // 6) amp MLP (M=256,K=256,N=8320)
    k_gemm<0><<<dim3(33, 4), 256, 0, stream>>>(w_amp1, 256, ampb, b_amp1, A1, 8320, 256, 0, 0, 0, 1);
    k_gemm<0><<<dim3(33, 4), 256, 0, stream>>>(w_amp2, 256, A1, b_amp2, A2, 8320, 256, 0, 0, 0, 0);

    // 7) irfft2 (z built in-register)
    k_c2c_inv<<<16640, 128, 0, stream>>>(A2, ifftb);
    k_c2r_row<<<32768, 128, 0, stream>>>(ifftb, fsmall);

    // 8) four path at low res: g1 = u1(fsmall)@128^2 ; g2 = u2(resize(g1))@256^2 ; h3 = Wc_a@g2
    k_gemm<0><<<dim3(64, 2), 256, 0, stream>>>(w_u1, 256, fsmall, b_u1, g1out, 16384, 256, 0, 0, 0, 0);
    k_gemm<2><<<dim3(256, 1), 256, 0, stream>>>(w_u2, 128, g1out, b_u2, g2out, 65536, 128, 8, 128, 128, 0);
    k_h3<<<256, 256, 0, stream>>>(g2out, Wc, h3);

    // 9) spat path: sp1,sp2 @128^2 ; g3 = u3(s2)@128^2 ; g4 = u4(resize(g3))@256^2
    k_gemm<0><<<dim3(64, 4), 256, 0, stream>>>(w_sp1, 256, xd2, b_sp1, s1, 16384, 256, 0, 0, 0, 1);
    k_gemm<0><<<dim3(64, 4), 256, 0, stream>>>(w_sp2, 256, s1, b_sp2, s2, 16384, 256, 0, 0, 0, 0);
    k_gemm<0><<<dim3(64, 2), 256, 0, stream>>>(w_u3, 256, s2, b_u3, g3out, 16384, 256, 0, 0, 0, 0);
    k_gemm<2><<<dim3(256, 1), 256, 0, stream>>>(w_u4, 128, g3out, b_u4, g4out, 65536, 128, 8, 128, 128, 0);

    // 10) final fused stage
    k_final<<<1024, 256, 0, stream>>>(x, dark, gmax, w_cf1, b_cf1, Wc, bc, g4out, h3, out);
}

// Round 7
// 844.193 us; speedup vs baseline: 2.0144x; 1.5359x over previous
//
#include <hip/hip_runtime.h>
#include <math.h>

#define PI_F 3.14159265358979323846f
#define NPIX 262144   // 512*512

typedef __attribute__((ext_vector_type(8))) short sh8;
typedef __attribute__((ext_vector_type(4))) float fx4;

__device__ __forceinline__ unsigned short f2bf(float v) {
    unsigned u = __float_as_uint(v);
    return (unsigned short)((u + 0x7FFFu + ((u >> 16) & 1)) >> 16);
}
__device__ __forceinline__ float bf2f(unsigned short h) {
    return __uint_as_float((unsigned)h << 16);
}

// ---------------------------------------------------------------- dark channel
__global__ __launch_bounds__(256) void k_minc(const float* __restrict__ x, float* __restrict__ dm,
                                              int* __restrict__ gmax) {
    int p = blockIdx.x * 256 + threadIdx.x;
    if (p == 0) gmax[0] = 0;
    float m = fmaxf(x[p], fmaxf(x[p + NPIX], x[p + 2 * NPIX]));
    dm[p] = 1.0f - m;
}

__device__ __forceinline__ int refl512(int t) {
    if (t < 0) t = -t;
    if (t > 511) t = 1022 - t;
    return t;
}

__global__ __launch_bounds__(256) void k_minrow(const float* __restrict__ dm, float* __restrict__ tmp) {
    int p = blockIdx.x * 256 + threadIdx.x;
    int i = p >> 9, j = p & 511;
    float m = 1e30f;
    #pragma unroll
    for (int d = -7; d <= 7; d++) m = fminf(m, dm[(i << 9) + refl512(j + d)]);
    tmp[p] = m;
}

__global__ __launch_bounds__(256) void k_mincol_max(const float* __restrict__ tmp, float* __restrict__ dark,
                                                    int* __restrict__ gmax) {
    int p = blockIdx.x * 256 + threadIdx.x;
    int i = p >> 9, j = p & 511;
    float m = 1e30f;
    #pragma unroll
    for (int d = -7; d <= 7; d++) m = fminf(m, tmp[(refl512(i + d) << 9) + j]);
    dark[p] = m;
    __shared__ float red[256];
    int tid = threadIdx.x;
    red[tid] = m;
    __syncthreads();
    for (int s = 128; s > 0; s >>= 1) {
        if (tid < s) red[tid] = fmaxf(red[tid], red[tid + s]);
        __syncthreads();
    }
    if (tid == 0) atomicMax(gmax, __float_as_int(red[0]));
}

// ---------------------------------------------------------------- Wc = w_cf3 @ w_cf2 (3x128), bc = w_cf3@b_cf2+b_cf3
__global__ __launch_bounds__(128) void k_wc(const float* __restrict__ w2, const float* __restrict__ b2,
                                            const float* __restrict__ w3, const float* __restrict__ b3,
                                            float* __restrict__ Wc, float* __restrict__ bc) {
    int j = threadIdx.x;  // 0..127
    for (int r = 0; r < 3; r++) {
        float s = 0.f;
        for (int o = 0; o < 64; o++) s += w3[r * 64 + o] * w2[o * 128 + j];
        Wc[r * 128 + j] = s;
    }
    if (j < 3) {
        float s = b3[j];
        for (int o = 0; o < 64; o++) s += w3[j * 64 + o] * b2[o];
        bc[j] = s;
    }
}

// ---------------------------------------------------------------- weight prep: fp32 [N][K(src)] -> bf16 (h and optional low), s2d K-permute
__global__ __launch_bounds__(256) void k_prepw(const float* __restrict__ w, unsigned short* __restrict__ h,
                                               unsigned short* __restrict__ l, int N, int K, int cshift) {
    int idx = blockIdx.x * 256 + threadIdx.x;
    if (idx >= N * K) return;
    int n = idx / K, kord = idx - n * K;
    int ksrc = kord;
    if (cshift) {
        int dydx = kord >> cshift, c = kord & ((1 << cshift) - 1);
        ksrc = c * 4 + dydx;
    }
    float v = w[n * K + ksrc];
    unsigned short hb = f2bf(v);
    h[idx] = hb;
    if (l) l[idx] = f2bf(v - bf2f(hb));
}

// ---------------------------------------------------------------- x_f = e2(e1(x)), channels-first (R3-verified)
__global__ __launch_bounds__(256) void k_ef(const float* __restrict__ x,
                                            const float* __restrict__ w1, const float* __restrict__ b1,
                                            const float* __restrict__ w2, const float* __restrict__ b2,
                                            float* __restrict__ out) {
    __shared__ float sw1[24], sb1[8], sw2[512], sb2[64];
    int tid = threadIdx.x;
    if (tid < 24) sw1[tid] = w1[tid];
    if (tid < 8)  sb1[tid] = b1[tid];
    if (tid < 64) sb2[tid] = b2[tid];
    if (tid < 256) { sw2[tid] = w2[tid]; sw2[tid + 256] = w2[tid + 256]; }
    __syncthreads();
    int p = blockIdx.x * 256 + tid;
    float x0 = x[p], x1 = x[p + NPIX], x2 = x[p + 2 * NPIX];
    float h[8];
    #pragma unroll
    for (int r = 0; r < 8; r++)
        h[r] = sw1[r * 3] * x0 + sw1[r * 3 + 1] * x1 + sw1[r * 3 + 2] * x2 + sb1[r];
    #pragma unroll 1
    for (int o = 0; o < 64; o++) {
        float acc = sb2[o];
        #pragma unroll
        for (int r = 0; r < 8; r++) acc += sw2[o * 8 + r] * h[r];
        out[(size_t)o * NPIX + p] = acc;
    }
}

// ---------------------------------------------------------------- channels-first MFMA GEMM (fresh rewrite)
// C[n][M+m] = sum_k W[n][k] * A[k][m] + bias[n]
// AMODE 0: A direct [K][M]; AMODE 1: s2d gather from channels-first src (Cin=2^cshift, out width 2^wshift, src srcW^2)
// SPLIT: bf16 h+l 3-mfma; LRELU on output.
template<int AMODE, int SPLIT, int LRELU>
__global__ __launch_bounds__(256) void k_mmcf(const float* __restrict__ Asrc,
                                              const unsigned short* __restrict__ Bh,
                                              const unsigned short* __restrict__ Bl,
                                              const float* __restrict__ bias, float* __restrict__ C,
                                              int M, int N, int K, int cshift, int wshift, int srcW) {
    __shared__ unsigned short AhS[128 * 40];
    __shared__ unsigned short BhS[64 * 40];
    __shared__ unsigned short AlS[SPLIT ? 128 * 40 : 8];
    __shared__ unsigned short BlS[SPLIT ? 64 * 40 : 8];
    int tid = threadIdx.x;
    int m0 = blockIdx.x * 128;
    int n0 = blockIdx.y * 64;
    int wave = tid >> 6, lane = tid & 63;
    int wm = (wave >> 1) * 64, wn = (wave & 1) * 32;
    int l15 = lane & 15, quad = lane >> 4;
    int lk = quad * 8, lk4 = quad * 4;
    fx4 acc[4][2];
    #pragma unroll
    for (int a = 0; a < 4; a++)
        #pragma unroll
        for (int b = 0; b < 2; b++)
            acc[a][b] = (fx4){0.f, 0.f, 0.f, 0.f};

    // A-staging assignment: thread -> (mm fixed, 8 k-pairs)
    int mm = tid & 127;
    int kpb = tid >> 7;          // 0/1
    int gm = m0 + mm;
    // precompute s2d pixel base pieces
    int oj = 0, oi = 0;
    if (AMODE == 1) { oj = gm & ((1 << wshift) - 1); oi = gm >> wshift; }

    for (int kb = 0; kb < K; kb += 32) {
        #pragma unroll
        for (int t = 0; t < 8; t++) {
            int kp = kpb + t * 2;          // [0,16)
            int k0 = kb + kp * 2;
            float a0, a1;
            if (AMODE == 0) {
                a0 = Asrc[(size_t)k0 * M + gm];
                a1 = Asrc[(size_t)(k0 + 1) * M + gm];
            } else {
                int c = k0 & ((1 << cshift) - 1);
                int dydx = k0 >> cshift;
                int dy = dydx >> 1, dx = dydx & 1;
                size_t pix = (size_t)(2 * oi + dy) * srcW + (2 * oj + dx);
                size_t plane = (size_t)srcW * srcW;
                a0 = Asrc[(size_t)c * plane + pix];          // k0 even -> c even, c+1 same dydx
                a1 = Asrc[(size_t)(c + 1) * plane + pix];
            }
            unsigned short h0 = f2bf(a0), h1 = f2bf(a1);
            *(unsigned*)(void*)&AhS[mm * 40 + kp * 2] = ((unsigned)h1 << 16) | (unsigned)h0;
            if (SPLIT) {
                unsigned short l0 = f2bf(a0 - bf2f(h0)), l1 = f2bf(a1 - bf2f(h1));
                *(unsigned*)(void*)&AlS[mm * 40 + kp * 2] = ((unsigned)l1 << 16) | (unsigned)l0;
            }
        }
        {
            int n = tid >> 2, seg = tid & 3;
            size_t gb = (size_t)(n0 + n) * K + kb + seg * 8;
            *(sh8*)(void*)&BhS[n * 40 + seg * 8] = *(const sh8*)(const void*)&Bh[gb];
            if (SPLIT) *(sh8*)(void*)&BlS[n * 40 + seg * 8] = *(const sh8*)(const void*)&Bl[gb];
        }
        __syncthreads();
        sh8 af[4], bf[2], afl[4], bfl[2];
        #pragma unroll
        for (int mt = 0; mt < 4; mt++) {
            af[mt] = *(const sh8*)(const void*)&AhS[(wm + mt * 16 + l15) * 40 + lk];
            if (SPLIT) afl[mt] = *(const sh8*)(const void*)&AlS[(wm + mt * 16 + l15) * 40 + lk];
        }
        #pragma unroll
        for (int nt = 0; nt < 2; nt++) {
            bf[nt] = *(const sh8*)(const void*)&BhS[(wn + nt * 16 + l15) * 40 + lk];
            if (SPLIT) bfl[nt] = *(const sh8*)(const void*)&BlS[(wn + nt * 16 + l15) * 40 + lk];
        }
        #pragma unroll
        for (int mt = 0; mt < 4; mt++)
            #pragma unroll
            for (int nt = 0; nt < 2; nt++) {
                acc[mt][nt] = __builtin_amdgcn_mfma_f32_16x16x32_bf16(af[mt], bf[nt], acc[mt][nt], 0, 0, 0);
                if (SPLIT) {
                    acc[mt][nt] = __builtin_amdgcn_mfma_f32_16x16x32_bf16(af[mt], bfl[nt], acc[mt][nt], 0, 0, 0);
                    acc[mt][nt] = __builtin_amdgcn_mfma_f32_16x16x32_bf16(afl[mt], bf[nt], acc[mt][nt], 0, 0, 0);
                }
            }
        __syncthreads();
    }
    // epilogue: D row(m) = quad*4+reg, col(n) = lane&15 -> float4 m-contiguous store
    #pragma unroll
    for (int nt = 0; nt < 2; nt++) {
        int n = n0 + wn + nt * 16 + l15;
        float bs = bias[n];
        #pragma unroll
        for (int mt = 0; mt < 4; mt++) {
            int mloc = m0 + wm + mt * 16 + lk4;
            float4 v;
            float* vp = (float*)&v;
            #pragma unroll
            for (int r = 0; r < 4; r++) {
                float q = acc[mt][nt][r] + bs;
                if (LRELU) q = (q < 0.f) ? 0.1f * q : q;
                vp[r] = q;
            }
            *(float4*)&C[(size_t)n * M + mloc] = v;
        }
    }
}

// ---------------------------------------------------------------- fp32 GEMM (R3-verified), used for u2/u4 resize-fused
template<int BMODE>
__global__ __launch_bounds__(256) void k_gemm(const float* __restrict__ A, int lda,
                                              const float* __restrict__ B,
                                              const float* __restrict__ bias,
                                              float* __restrict__ C,
                                              int N, int K,
                                              int wshift, int srcH, int srcW, int flags) {
    __shared__ float As[8][64];
    __shared__ float Bs[8][256];
    int tid = threadIdx.x;
    int tx = tid & 31, ty = tid >> 5;
    int n0 = blockIdx.x * 256;
    int m0 = blockIdx.y * 64;
    float acc[8][8] = {};
    for (int kb = 0; kb < K; kb += 8) {
        #pragma unroll
        for (int e = 0; e < 2; e++) {
            int i = e * 256 + tid;
            int mm = i & 63, kk = i >> 6;
            As[kk][mm] = A[(size_t)(m0 + mm) * lda + kb + kk];
        }
        #pragma unroll
        for (int e = 0; e < 8; e++) {
            int i = e * 256 + tid;
            int nn = i & 255, kk = i >> 8;
            int k = kb + kk, n = n0 + nn;
            float v = 0.f;
            if (BMODE == 0) {
                if (n < N) v = B[(size_t)k * N + n];
            } else if (BMODE == 1) {
                int c = k >> 2, dy = (k >> 1) & 1, dx = k & 1;
                int jj = n & ((1 << wshift) - 1), ii = n >> wshift;
                v = B[((size_t)c * srcH + (2 * ii + dy)) * srcW + (2 * jj + dx)];
            } else {
                int jj = n & ((1 << wshift) - 1), ii = n >> wshift;
                const float* p = B + (size_t)k * srcH * srcW;
                int ky = ii >> 1, ylo, yhi; float wyl, wyh;
                if ((ii & 1) == 0) { ylo = ky - 1; yhi = ky; wyl = .25f; wyh = .75f; if (ylo < 0) { ylo = 0; wyl = 0.f; wyh = 1.f; } }
                else               { ylo = ky; yhi = ky + 1; wyl = .75f; wyh = .25f; if (yhi > srcH - 1) { yhi = srcH - 1; wyh = 0.f; wyl = 1.f; } }
                int kx = jj >> 1, xlo, xhi; float wxl, wxh;
                if ((jj & 1) == 0) { xlo = kx - 1; xhi = kx; wxl = .25f; wxh = .75f; if (xlo < 0) { xlo = 0; wxl = 0.f; wxh = 1.f; } }
                else               { xlo = kx; xhi = kx + 1; wxl = .75f; wxh = .25f; if (xhi > srcW - 1) { xhi = srcW - 1; wxh = 0.f; wxl = 1.f; } }
                v = wyl * (wxl * p[(size_t)ylo * srcW + xlo] + wxh * p[(size_t)ylo * srcW + xhi]) +
                    wyh * (wxl * p[(size_t)yhi * srcW + xlo] + wxh * p[(size_t)yhi * srcW + xhi]);
            }
            Bs[kk][nn] = v;
        }
        __syncthreads();
        #pragma unroll
        for (int kk = 0; kk < 8; kk++) {
            float4 A0 = *(const float4*)&As[kk][ty * 8];
            float4 A1 = *(const float4*)&As[kk][ty * 8 + 4];
            float4 B0 = *(const float4*)&Bs[kk][tx * 4];
            float4 B1 = *(const float4*)&Bs[kk][128 + tx * 4];
            float av[8] = {A0.x, A0.y, A0.z, A0.w, A1.x, A1.y, A1.z, A1.w};
            float bv[8] = {B0.x, B0.y, B0.z, B0.w, B1.x, B1.y, B1.z, B1.w};
            #pragma unroll
            for (int r = 0; r < 8; r++)
                #pragma unroll
                for (int s = 0; s < 8; s++)
                    acc[r][s] += av[r] * bv[s];
        }
        __syncthreads();
    }
    int n1 = n0 + tx * 4, n2 = n0 + 128 + tx * 4;
    #pragma unroll
    for (int r = 0; r < 8; r++) {
        int m = m0 + ty * 8 + r;
        float bs = bias ? bias[m] : 0.f;
        float o[8];
        #pragma unroll
        for (int s = 0; s < 8; s++) {
            float v = acc[r][s] + bs;
            if (flags & 1) v = (v < 0.f) ? 0.1f * v : v;
            o[s] = v;
        }
        size_t rowb = (size_t)m * N;
        if (n1 < N) *(float4*)&C[rowb + n1] = make_float4(o[0], o[1], o[2], o[3]);
        if (n2 < N) *(float4*)&C[rowb + n2] = make_float4(o[4], o[5], o[6], o[7]);
    }
}

// ---------------------------------------------------------------- DFT kernels (fp32, channels-first; R3-verified)
__global__ __launch_bounds__(128) void k_r2c_row(const float* __restrict__ in, float2* __restrict__ out) {
    __shared__ float s[128];
    int b = blockIdx.x;
    int t = threadIdx.x;
    s[t] = in[(size_t)b * 128 + t];
    __syncthreads();
    if (t < 65) {
        float ang = -2.f * PI_F * (float)t / 128.f;
        float stepr, stepi;
        sincosf(ang, &stepi, &stepr);
        float re = 0.f, im = 0.f, cr = 1.f, ci = 0.f;
        for (int n = 0; n < 128; n++) {
            float v = s[n];
            re += v * cr;
            im += v * ci;
            float nr = cr * stepr - ci * stepi;
            ci = cr * stepi + ci * stepr;
            cr = nr;
        }
        out[(size_t)b * 65 + t] = make_float2(re, im);
    }
}

__global__ __launch_bounds__(128) void k_c2c_amp(const float2* __restrict__ in, float* __restrict__ amp) {
    __shared__ float2 s[128];
    int b = blockIdx.x;
    int c = b / 65, k = b - c * 65;
    int t = threadIdx.x;
    s[t] = in[((size_t)c * 128 + t) * 65 + k];
    __syncthreads();
    float ang = -2.f * PI_F * (float)t / 128.f;
    float stepr, stepi;
    sincosf(ang, &stepi, &stepr);
    float re = 0.f, im = 0.f, cr = 1.f, ci = 0.f;
    for (int m = 0; m < 128; m++) {
        float2 z = s[m];
        re += z.x * cr - z.y * ci;
        im += z.x * ci + z.y * cr;
        float nr = cr * stepr - ci * stepi;
        ci = cr * stepi + ci * stepr;
        cr = nr;
    }
    amp[((size_t)c * 128 + t) * 65 + k] = sqrtf(re * re + im * im);
}

__global__ __launch_bounds__(128) void k_c2c_inv(const float* __restrict__ amp2, float2* __restrict__ out) {
    __shared__ float2 s[128];
    int b = blockIdx.x;
    int c = b / 65, k = b - c * 65;
    int t = threadIdx.x;
    float a = amp2[((size_t)c * 128 + t) * 65 + k];
    float zs, zc;
    sincosf(a, &zs, &zc);
    s[t] = make_float2(a * zc, a * zs);
    __syncthreads();
    float ang = 2.f * PI_F * (float)t / 128.f;
    float stepr, stepi;
    sincosf(ang, &stepi, &stepr);
    float re = 0.f, im = 0.f, cr = 1.f, ci = 0.f;
    for (int m = 0; m < 128; m++) {
        float2 z = s[m];
        re += z.x * cr - z.y * ci;
        im += z.x * ci + z.y * cr;
        float nr = cr * stepr - ci * stepi;
        ci = cr * stepi + ci * stepr;
        cr = nr;
    }
    out[((size_t)c * 128 + t) * 65 + k] = make_float2(re * (1.f / 128.f), im * (1.f / 128.f));
}

__global__ __launch_bounds__(128) void k_c2r_row(const float2* __restrict__ in, float* __restrict__ out) {
    __shared__ float2 s[65];
    int b = blockIdx.x;
    int t = threadIdx.x;
    if (t < 65) s[t] = in[(size_t)b * 65 + t];
    __syncthreads();
    float ang = 2.f * PI_F * (float)t / 128.f;
    float stepr, stepi;
    sincosf(ang, &stepi, &stepr);
    float cr = stepr, ci = stepi;
    float acc = 0.f;
    for (int k = 1; k < 64; k++) {
        float2 z = s[k];
        acc += z.x * cr - z.y * ci;
        float nr = cr * stepr - ci * stepi;
        ci = cr * stepi + ci * stepr;
        cr = nr;
    }
    acc += 0.5f * s[0].x;
    acc += ((t & 1) ? -0.5f : 0.5f) * s[64].x;
    out[(size_t)b * 128 + t] = acc * (2.f / 128.f);
}

// ---------------------------------------------------------------- h3 = Wc[:, :64] @ g2 (channels-first; R3-verified)
__global__ __launch_bounds__(256) void k_h3(const float* __restrict__ g2, const float* __restrict__ Wc,
                                            float* __restrict__ h3) {
    __shared__ float wa[192];
    int tid = threadIdx.x;
    if (tid < 192) { int r = tid >> 6, c = tid & 63; wa[tid] = Wc[r * 128 + c]; }
    __syncthreads();
    int q = blockIdx.x * 256 + tid;
    float a0 = 0.f, a1 = 0.f, a2 = 0.f;
    #pragma unroll 4
    for (int c = 0; c < 64; c++) {
        float v = g2[(size_t)c * 65536 + q];
        a0 += wa[c] * v;
        a1 += wa[64 + c] * v;
        a2 += wa[128 + c] * v;
    }
    h3[q] = a0; h3[65536 + q] = a1; h3[131072 + q] = a2;
}

// ---------------------------------------------------------------- final fused stage @512^2 (R3-verified)
__global__ __launch_bounds__(256) void k_final(const float* __restrict__ x,
                                               const float* __restrict__ dark, const int* __restrict__ gmax,
                                               const float* __restrict__ wcf1, const float* __restrict__ bcf1,
                                               const float* __restrict__ Wc, const float* __restrict__ bc,
                                               const float* __restrict__ g4, const float* __restrict__ h3,
                                               float* __restrict__ out) {
    __shared__ float dimt[32], w1[192], b1[64], wb[192], bcs[3];
    int tid = threadIdx.x;
    if (tid < 32) dimt[tid] = powf(10000.f, (float)(2 * (tid >> 1)) / 32.f);
    if (tid < 192) w1[tid] = wcf1[tid];
    if (tid < 64) b1[tid] = bcf1[tid];
    if (tid < 192) { int r = tid / 64, c = tid - (tid / 64) * 64; wb[tid] = Wc[r * 128 + 64 + c]; }
    if (tid < 3) bcs[tid] = bc[tid];
    __syncthreads();
    int p = blockIdx.x * 256 + tid;
    int i = p >> 9, j = p & 511;
    const float scale = 2.f * PI_F;
    float inv511 = scale / (511.f + 1e-6f);
    float xe = (float)j * inv511, ye = (float)i * inv511;
    float gm = __int_as_float(gmax[0]);
    float ze = dark[p] / (gm + 1e-6f) * scale;
    float x0 = x[p], x1 = x[p + NPIX], x2 = x[p + 2 * NPIX];

    int ky = i >> 1, ylo, yhi; float wyl, wyh;
    if ((i & 1) == 0) { ylo = ky - 1; yhi = ky; wyl = .25f; wyh = .75f; if (ylo < 0) { ylo = 0; wyl = 0.f; wyh = 1.f; } }
    else              { ylo = ky; yhi = ky + 1; wyl = .75f; wyh = .25f; if (yhi > 255) { yhi = 255; wyh = 0.f; wyl = 1.f; } }
    int kx = j >> 1, xlo, xhi; float wxl, wxh;
    if ((j & 1) == 0) { xlo = kx - 1; xhi = kx; wxl = .25f; wxh = .75f; if (xlo < 0) { xlo = 0; wxl = 0.f; wxh = 1.f; } }
    else              { xlo = kx; xhi = kx + 1; wxl = .75f; wxh = .25f; if (xhi > 255) { xhi = 255; wxh = 0.f; wxl = 1.f; } }
    int s00 = ylo * 256 + xlo, s01 = ylo * 256 + xhi, s10 = yhi * 256 + xlo, s11 = yhi * 256 + xhi;
    float w00 = wyl * wxl, w01 = wyl * wxh, w10 = wyh * wxl, w11 = wyh * wxh;

    float a0 = 0.f, a1 = 0.f, a2 = 0.f;
    #pragma unroll 1
    for (int c = 0; c < 64; c++) {
        float e = (c < 16) ? xe / dimt[c] : (c < 32) ? ye / dimt[c - 16] : ze / dimt[c - 32];
        float sn, cs;
        __sincosf(e, &sn, &cs);
        float pos = ((c & 1) == 0) ? sn : cs;
        float ape = pos + w1[c * 3] * x0 + w1[c * 3 + 1] * x1 + w1[c * 3 + 2] * x2 + b1[c];
        const float* gp = g4 + (size_t)c * 65536;
        float gv = w00 * gp[s00] + w01 * gp[s01] + w10 * gp[s10] + w11 * gp[s11];
        float s = gv * ape;
        a0 += wb[c] * s; a1 += wb[64 + c] * s; a2 += wb[128 + c] * s;
    }
    float f0 = w00 * h3[s00] + w01 * h3[s01] + w10 * h3[s10] + w11 * h3[s11];
    const float* h1 = h3 + 65536;
    float f1 = w00 * h1[s00] + w01 * h1[s01] + w10 * h1[s10] + w11 * h1[s11];
    const float* h2 = h3 + 131072;
    float f2 = w00 * h2[s00] + w01 * h2[s01] + w10 * h2[s10] + w11 * h2[s11];
    out[p]            = a0 + f0 + bcs[0] + x0;
    out[NPIX + p]     = a1 + f1 + bcs[1] + x1;
    out[2 * NPIX + p] = a2 + f2 + bcs[2] + x2;
}

// ================================================================ launcher
extern "C" void kernel_launch(void* const* d_in, const int* in_sizes, int n_in,
                              void* d_out, int out_size, void* d_ws, size_t ws_size,
                              hipStream_t stream) {
    const float* x      = (const float*)d_in[0];
    const float* w_cf1  = (const float*)d_in[1];  const float* b_cf1 = (const float*)d_in[2];
    const float* w_e1   = (const float*)d_in[3];  const float* b_e1  = (const float*)d_in[4];
    const float* w_e2   = (const float*)d_in[5];  const float* b_e2  = (const float*)d_in[6];
    const float* w_d1   = (const float*)d_in[7];  const float* b_d1  = (const float*)d_in[8];
    const float* w_d2   = (const float*)d_in[9];  const float* b_d2  = (const float*)d_in[10];
    // 11..14: pha branch is dead code in the reference
    const float* w_amp1 = (const float*)d_in[15]; const float* b_amp1 = (const float*)d_in[16];
    const float* w_amp2 = (const float*)d_in[17]; const float* b_amp2 = (const float*)d_in[18];
    const float* w_sp1  = (const float*)d_in[19]; const float* b_sp1  = (const float*)d_in[20];
    const float* w_sp2  = (const float*)d_in[21]; const float* b_sp2  = (const float*)d_in[22];
    const float* w_u1   = (const float*)d_in[23]; const float* b_u1   = (const float*)d_in[24];
    const float* w_u2   = (const float*)d_in[25]; const float* b_u2   = (const float*)d_in[26];
    const float* w_u3   = (const float*)d_in[27]; const float* b_u3   = (const float*)d_in[28];
    const float* w_u4   = (const float*)d_in[29]; const float* b_u4   = (const float*)d_in[30];
    const float* w_cf2  = (const float*)d_in[31]; const float* b_cf2  = (const float*)d_in[32];
    const float* w_cf3  = (const float*)d_in[33]; const float* b_cf3  = (const float*)d_in[34];
    float* out = (float*)d_out;

    // ---- workspace layout: R3's verified layout + bf16 weight arena at [192,194) ----
    char* ws = (char*)d_ws;
    constexpr size_t MiB = 1ull << 20;
    float*  dark   = (float*)(ws + 0 * MiB);
    float*  tmp    = (float*)(ws + 1 * MiB);
    int*    gmax   = (int*)  (ws + 2 * MiB);
    float*  Wc     = (float*)(ws + 2 * MiB + 1024);
    float*  bc     = (float*)(ws + 2 * MiB + 1024 + 1536);
    float*  xf     = (float*)(ws + 3 * MiB);     // 64 MiB [3,67)
    float*  xd1    = (float*)(ws + 67 * MiB);    // 32 MiB [67,99)
    float*  xd2    = (float*)(ws + 99 * MiB);    // 16 MiB [99,115)
    float2* rowfft = (float2*)(ws + 115 * MiB);  // 16.25 [115,131.25)
    float*  ampb   = (float*)(ws + 132 * MiB);   // 8.125 [132,140.125)
    float*  A1     = (float*)(ws + 115 * MiB);   // 8.125 (rowfft dead)
    float*  A2     = (float*)(ws + 124 * MiB);   // 8.125 [124,132.125)
    float2* ifftb  = (float2*)(ws + 133 * MiB);  // 16.25 [133,149.25)
    float*  fsmall = (float*)(ws + 115 * MiB);   // 16 [115,131) (A1 dead)
    float*  g1out  = (float*)(ws + 3 * MiB);     // 8  [3,11)  (xf dead after d1)
    float*  g2out  = (float*)(ws + 11 * MiB);    // 16 [11,27)
    float*  h3     = (float*)(ws + 27 * MiB);    // 0.75
    float*  s1     = (float*)(ws + 31 * MiB);    // 16 [31,47)
    float*  s2     = (float*)(ws + 47 * MiB);    // 16 [47,63)
    float*  g3out  = (float*)(ws + 63 * MiB);    // 8  [63,71) (xd1 dead)
    float*  g4out  = (float*)(ws + 71 * MiB);    // 16 [71,87)
    unsigned short* wb16 = (unsigned short*)(ws + 192 * MiB);  // [192,194)
    unsigned short* d1h = wb16 + 0,      * d1l = wb16 + 32768;
    unsigned short* d2h = wb16 + 65536,  * d2l = wb16 + 196608;
    unsigned short* a1h = wb16 + 327680, * a1l = wb16 + 393216;
    unsigned short* a2h = wb16 + 458752, * a2l = wb16 + 524288;
    unsigned short* s1h = wb16 + 589824;
    unsigned short* s2h = wb16 + 655360;
    unsigned short* u1h = wb16 + 720896;
    unsigned short* u3h = wb16 + 753664;   // ends 786432 < 1M shorts

    // 1) dark channel + gmax + composed cf weights + weight prep
    k_minc<<<1024, 256, 0, stream>>>(x, dark, gmax);
    k_minrow<<<1024, 256, 0, stream>>>(dark, tmp);
    k_mincol_max<<<1024, 256, 0, stream>>>(tmp, dark, gmax);
    k_wc<<<1, 128, 0, stream>>>(w_cf2, b_cf2, w_cf3, b_cf3, Wc, bc);
    k_prepw<<<128, 256, 0, stream>>>(w_d1, d1h, d1l, 128, 256, 6);
    k_prepw<<<512, 256, 0, stream>>>(w_d2, d2h, d2l, 256, 512, 7);
    k_prepw<<<256, 256, 0, stream>>>(w_amp1, a1h, a1l, 256, 256, 0);
    k_prepw<<<256, 256, 0, stream>>>(w_amp2, a2h, a2l, 256, 256, 0);
    k_prepw<<<256, 256, 0, stream>>>(w_sp1, s1h, nullptr, 256, 256, 0);
    k_prepw<<<256, 256, 0, stream>>>(w_sp2, s2h, nullptr, 256, 256, 0);
    k_prepw<<<128, 256, 0, stream>>>(w_u1, u1h, nullptr, 128, 256, 0);
    k_prepw<<<128, 256, 0, stream>>>(w_u3, u3h, nullptr, 128, 256, 0);

    // 2) x_f channels-first
    k_ef<<<1024, 256, 0, stream>>>(x, w_e1, b_e1, w_e2, b_e2, xf);

    // 3) d1 (MFMA split, s2d): M=65536 pix @256^2, N=128, K=256
    k_mmcf<1, 1, 0><<<dim3(512, 2), 256, 0, stream>>>(xf, d1h, d1l, b_d1, xd1, 65536, 128, 256, 6, 8, 512);
    // 4) d2 (MFMA split, s2d): M=16384 @128^2, N=256, K=512
    k_mmcf<1, 1, 0><<<dim3(128, 4), 256, 0, stream>>>(xd1, d2h, d2l, b_d2, xd2, 16384, 256, 512, 7, 7, 256);

    // 5) forward rfft2 -> amp
    k_r2c_row<<<32768, 128, 0, stream>>>(xd2, rowfft);
    k_c2c_amp<<<16640, 128, 0, stream>>>(rowfft, ampb);

    // 6) amp MLP (MFMA split, channels-first, no transposes): M=8320, N=256, K=256
    k_mmcf<0, 1, 1><<<dim3(65, 4), 256, 0, stream>>>(ampb, a1h, a1l, b_amp1, A1, 8320, 256, 256, 0, 0, 0);
    k_mmcf<0, 1, 0><<<dim3(65, 4), 256, 0, stream>>>(A1, a2h, a2l, b_amp2, A2, 8320, 256, 256, 0, 0, 0);

    // 7) irfft2 (z built in-register)
    k_c2c_inv<<<16640, 128, 0, stream>>>(A2, ifftb);
    k_c2r_row<<<32768, 128, 0, stream>>>(ifftb, fsmall);

    // 8) four path: u1 (MFMA) @128^2 ; u2 fp32 fused-resize @256^2 ; h3
    k_mmcf<0, 0, 0><<<dim3(128, 2), 256, 0, stream>>>(fsmall, u1h, nullptr, b_u1, g1out, 16384, 128, 256, 0, 0, 0);
    k_gemm<2><<<dim3(256, 1), 256, 0, stream>>>(w_u2, 128, g1out, b_u2, g2out, 65536, 128, 8, 128, 128, 0);
    k_h3<<<256, 256, 0, stream>>>(g2out, Wc, h3);

    // 9) spat path: sp1,sp2,u3 (MFMA) @128^2 ; u4 fp32 fused-resize @256^2
    k_mmcf<0, 0, 1><<<dim3(128, 4), 256, 0, stream>>>(xd2, s1h, nullptr, b_sp1, s1, 16384, 256, 256, 0, 0, 0);
    k_mmcf<0, 0, 0><<<dim3(128, 4), 256, 0, stream>>>(s1, s2h, nullptr, b_sp2, s2, 16384, 256, 256, 0, 0, 0);
    k_mmcf<0, 0, 0><<<dim3(128, 2), 256, 0, stream>>>(s2, u3h, nullptr, b_u3, g3out, 16384, 128, 256, 0, 0, 0);
    k_gemm<2><<<dim3(256, 1), 256, 0, stream>>>(w_u4, 128, g3out, b_u4, g4out, 65536, 128, 8, 128, 128, 0);

    // 10) final fused stage
    k_final<<<1024, 256, 0, stream>>>(x, dark, gmax, w_cf1, b_cf1, Wc, bc, g4out, h3, out);
}

// Round 8
// 727.981 us; speedup vs baseline: 2.3360x; 1.1596x over previous
//
#include <hip/hip_runtime.h>
#include <math.h>

#define PI_F 3.14159265358979323846f
#define NPIX 262144   // 512*512

typedef __attribute__((ext_vector_type(8))) short sh8;
typedef __attribute__((ext_vector_type(4))) float fx4;

__device__ __forceinline__ unsigned short f2bf(float v) {
    unsigned u = __float_as_uint(v);
    return (unsigned short)((u + 0x7FFFu + ((u >> 16) & 1)) >> 16);
}
__device__ __forceinline__ float bf2f(unsigned short h) {
    return __uint_as_float((unsigned)h << 16);
}

// ---------------------------------------------------------------- dark channel
__global__ __launch_bounds__(256) void k_minc(const float* __restrict__ x, float* __restrict__ dm,
                                              int* __restrict__ gmax) {
    int p = blockIdx.x * 256 + threadIdx.x;
    if (p == 0) gmax[0] = 0;
    float m = fmaxf(x[p], fmaxf(x[p + NPIX], x[p + 2 * NPIX]));
    dm[p] = 1.0f - m;
}

__device__ __forceinline__ int refl512(int t) {
    if (t < 0) t = -t;
    if (t > 511) t = 1022 - t;
    return t;
}

__global__ __launch_bounds__(256) void k_minrow(const float* __restrict__ dm, float* __restrict__ tmp) {
    int p = blockIdx.x * 256 + threadIdx.x;
    int i = p >> 9, j = p & 511;
    float m = 1e30f;
    #pragma unroll
    for (int d = -7; d <= 7; d++) m = fminf(m, dm[(i << 9) + refl512(j + d)]);
    tmp[p] = m;
}

__global__ __launch_bounds__(256) void k_mincol_max(const float* __restrict__ tmp, float* __restrict__ dark,
                                                    int* __restrict__ gmax) {
    int p = blockIdx.x * 256 + threadIdx.x;
    int i = p >> 9, j = p & 511;
    float m = 1e30f;
    #pragma unroll
    for (int d = -7; d <= 7; d++) m = fminf(m, tmp[(refl512(i + d) << 9) + j]);
    dark[p] = m;
    __shared__ float red[256];
    int tid = threadIdx.x;
    red[tid] = m;
    __syncthreads();
    for (int s = 128; s > 0; s >>= 1) {
        if (tid < s) red[tid] = fmaxf(red[tid], red[tid + s]);
        __syncthreads();
    }
    if (tid == 0) atomicMax(gmax, __float_as_int(red[0]));
}

// ---------------------------------------------------------------- Wc = w_cf3 @ w_cf2 (3x128), bc
__global__ __launch_bounds__(128) void k_wc(const float* __restrict__ w2, const float* __restrict__ b2,
                                            const float* __restrict__ w3, const float* __restrict__ b3,
                                            float* __restrict__ Wc, float* __restrict__ bc) {
    int j = threadIdx.x;
    for (int r = 0; r < 3; r++) {
        float s = 0.f;
        for (int o = 0; o < 64; o++) s += w3[r * 64 + o] * w2[o * 128 + j];
        Wc[r * 128 + j] = s;
    }
    if (j < 3) {
        float s = b3[j];
        for (int o = 0; o < 64; o++) s += w3[j * 64 + o] * b2[o];
        bc[j] = s;
    }
}

// ---------------------------------------------------------------- weight prep
__global__ __launch_bounds__(256) void k_prepw(const float* __restrict__ w, unsigned short* __restrict__ h,
                                               unsigned short* __restrict__ l, int N, int K, int cshift) {
    int idx = blockIdx.x * 256 + threadIdx.x;
    if (idx >= N * K) return;
    int n = idx / K, kord = idx - n * K;
    int ksrc = kord;
    if (cshift) {
        int dydx = kord >> cshift, c = kord & ((1 << cshift) - 1);
        ksrc = c * 4 + dydx;
    }
    float v = w[n * K + ksrc];
    unsigned short hb = f2bf(v);
    h[idx] = hb;
    if (l) l[idx] = f2bf(v - bf2f(hb));
}

// ---------------------------------------------------------------- DFT B-matrix builder (split bf16, exact mod-128 angles)
__global__ __launch_bounds__(256) void k_bfft(unsigned short* __restrict__ BfH, unsigned short* __restrict__ BfL,
                                              unsigned short* __restrict__ BfcH, unsigned short* __restrict__ BfcL,
                                              unsigned short* __restrict__ BicH, unsigned short* __restrict__ BicL,
                                              unsigned short* __restrict__ BirH, unsigned short* __restrict__ BirL,
                                              float* __restrict__ zbias) {
    int idx = blockIdx.x * 256 + threadIdx.x;
    if (idx < 256) zbias[idx] = 0.f;
    const float w0 = 2.f * PI_F / 128.f;
    float v;
    unsigned short *H, *L;
    int off;
    if (idx < 32768) {                     // Bf [256][128]: rows<128 = cos(forward), rows>=128 = -sin
        int n = idx >> 7, k = idx & 127;
        int t = n & 127, r = (t * k) & 127;
        float s_, c_; sincosf(w0 * r, &s_, &c_);
        v = (n < 128) ? c_ : -s_;
        H = BfH; L = BfL; off = idx;
    } else if (idx < 98304) {              // Bfc [256][256]: fwd col, e^{-i}: re=[cos|sin], im=[-sin|cos]
        int i = idx - 32768;
        int n = i >> 8, j = i & 255;
        int t = n & 127, r = (t * (j & 127)) & 127;
        float s_, c_; sincosf(w0 * r, &s_, &c_);
        v = (n < 128) ? ((j < 128) ? c_ : s_) : ((j < 128) ? -s_ : c_);
        H = BfcH; L = BfcL; off = i;
    } else if (idx < 163840) {             // Bic [256][256]: inv col, e^{+i}/128: re=[cos|-sin], im=[sin|cos]
        int i = idx - 98304;
        int n = i >> 8, j = i & 255;
        int t = n & 127, r = (t * (j & 127)) & 127;
        float s_, c_; sincosf(w0 * r, &s_, &c_);
        v = ((n < 128) ? ((j < 128) ? c_ : -s_) : ((j < 128) ? s_ : c_)) * (1.f / 128.f);
        H = BicH; L = BicL; off = i;
    } else if (idx < 184320) {             // Bir [128][160]: hermitian c2r row (verified k_c2r_row math)
        int i = idx - 163840;
        int col = i / 160, j = i - col * 160;
        if (j == 0) v = 1.f / 128.f;
        else if (j < 64)  { int r = (j * col) & 127; float s_, c_; sincosf(w0 * r, &s_, &c_); v = 2.f * c_ / 128.f; }
        else if (j == 64) v = (col & 1) ? -1.f / 128.f : 1.f / 128.f;
        else if (j >= 66 && j <= 128) { int k = j - 65; int r = (k * col) & 127; float s_, c_; sincosf(w0 * r, &s_, &c_); v = -2.f * s_ / 128.f; }
        else v = 0.f;                      // j==65 (wim[0]), j==129 (wim[64]), j>=130 pad
        H = BirH; L = BirL; off = i;
    } else return;
    unsigned short hb = f2bf(v);
    H[off] = hb;
    L[off] = f2bf(v - bf2f(hb));
}

// ---------------------------------------------------------------- x_f = e2(e1(x)), channels-first
__global__ __launch_bounds__(256) void k_ef(const float* __restrict__ x,
                                            const float* __restrict__ w1, const float* __restrict__ b1,
                                            const float* __restrict__ w2, const float* __restrict__ b2,
                                            float* __restrict__ out) {
    __shared__ float sw1[24], sb1[8], sw2[512], sb2[64];
    int tid = threadIdx.x;
    if (tid < 24) sw1[tid] = w1[tid];
    if (tid < 8)  sb1[tid] = b1[tid];
    if (tid < 64) sb2[tid] = b2[tid];
    if (tid < 256) { sw2[tid] = w2[tid]; sw2[tid + 256] = w2[tid + 256]; }
    __syncthreads();
    int p = blockIdx.x * 256 + tid;
    float x0 = x[p], x1 = x[p + NPIX], x2 = x[p + 2 * NPIX];
    float h[8];
    #pragma unroll
    for (int r = 0; r < 8; r++)
        h[r] = sw1[r * 3] * x0 + sw1[r * 3 + 1] * x1 + sw1[r * 3 + 2] * x2 + sb1[r];
    #pragma unroll 1
    for (int o = 0; o < 64; o++) {
        float acc = sb2[o];
        #pragma unroll
        for (int r = 0; r < 8; r++) acc += sw2[o * 8 + r] * h[r];
        out[(size_t)o * NPIX + p] = acc;
    }
}

// ---------------------------------------------------------------- channels-first MFMA GEMM (R7-verified core)
// C[n][M+m] = sum_k B[n][k] * A(k, m) + bias[n]
// AMODE 0: A[k][m] row-major [K][M]
// AMODE 1: s2d gather from channels-first src
// AMODE 3: A[m][K] row-major (lda = K)
// AMODE 4: F2 col-fwd gather: c=gm/65, kf=gm%65; addr = kf*32768 + c*128 + (j<128 ? j : 4194304 + j-128)
// AMODE 5: I2 c2r gather: addr = (gm&127)*16640 + (gm>>7)*65 + (j<65 ? j : 2129920 + j-65)
// AMODE 6: u1 gather from I2 output [col][c][t]: addr = (gm&127)*32768 + k*128 + (gm>>7)
template<int AMODE, int SPLIT, int LRELU>
__global__ __launch_bounds__(256) void k_mmcf(const float* __restrict__ Asrc,
                                              const unsigned short* __restrict__ Bh,
                                              const unsigned short* __restrict__ Bl,
                                              const float* __restrict__ bias, float* __restrict__ C,
                                              int M, int N, int K, int cshift, int wshift, int srcW) {
    __shared__ unsigned short AhS[128 * 40];
    __shared__ unsigned short BhS[64 * 40];
    __shared__ unsigned short AlS[SPLIT ? 128 * 40 : 8];
    __shared__ unsigned short BlS[SPLIT ? 64 * 40 : 8];
    int tid = threadIdx.x;
    int m0 = blockIdx.x * 128;
    int n0 = blockIdx.y * 64;
    int wave = tid >> 6, lane = tid & 63;
    int wm = (wave >> 1) * 64, wn = (wave & 1) * 32;
    int l15 = lane & 15, quad = lane >> 4;
    int lk = quad * 8, lk4 = quad * 4;
    fx4 acc[4][2];
    #pragma unroll
    for (int a = 0; a < 4; a++)
        #pragma unroll
        for (int b = 0; b < 2; b++)
            acc[a][b] = (fx4){0.f, 0.f, 0.f, 0.f};

    int mm = tid & 127;
    int kpb = tid >> 7;          // 0/1
    int gm = m0 + mm;
    int oj = 0, oi = 0;
    size_t abase = 0;
    if (AMODE == 1) { oj = gm & ((1 << wshift) - 1); oi = gm >> wshift; }
    if (AMODE == 3) { abase = (size_t)gm * K; }
    if (AMODE == 4) { int c = gm / 65, kf = gm - c * 65; abase = (size_t)kf * 32768 + (size_t)c * 128; }
    if (AMODE == 5) { abase = (size_t)(gm & 127) * 16640 + (size_t)(gm >> 7) * 65; }
    if (AMODE == 6) { abase = (size_t)(gm & 127) * 32768 + (size_t)(gm >> 7); }

    for (int kb = 0; kb < K; kb += 32) {
        #pragma unroll
        for (int t = 0; t < 8; t++) {
            int kp = kpb + t * 2;          // [0,16)
            int k0 = kb + kp * 2;
            float a0, a1;
            if (AMODE == 0) {
                a0 = Asrc[(size_t)k0 * M + gm];
                a1 = Asrc[(size_t)(k0 + 1) * M + gm];
            } else if (AMODE == 1) {
                int c = k0 & ((1 << cshift) - 1);
                int dydx = k0 >> cshift;
                int dy = dydx >> 1, dx = dydx & 1;
                size_t pix = (size_t)(2 * oi + dy) * srcW + (2 * oj + dx);
                size_t plane = (size_t)srcW * srcW;
                a0 = Asrc[(size_t)c * plane + pix];
                a1 = Asrc[(size_t)(c + 1) * plane + pix];
            } else if (AMODE == 3) {
                a0 = Asrc[abase + k0];
                a1 = Asrc[abase + k0 + 1];
            } else if (AMODE == 4) {
                int j0 = k0, j1 = k0 + 1;
                a0 = Asrc[abase + (j0 < 128 ? j0 : 4194304 + (j0 - 128))];
                a1 = Asrc[abase + (j1 < 128 ? j1 : 4194304 + (j1 - 128))];
            } else if (AMODE == 5) {
                int j0 = k0, j1 = k0 + 1;
                a0 = Asrc[abase + (j0 < 65 ? j0 : 2129920 + (j0 - 65))];
                a1 = Asrc[abase + (j1 < 65 ? j1 : 2129920 + (j1 - 65))];
            } else {
                a0 = Asrc[abase + (size_t)k0 * 128];
                a1 = Asrc[abase + (size_t)(k0 + 1) * 128];
            }
            unsigned short h0 = f2bf(a0), h1 = f2bf(a1);
            *(unsigned*)(void*)&AhS[mm * 40 + kp * 2] = ((unsigned)h1 << 16) | (unsigned)h0;
            if (SPLIT) {
                unsigned short l0 = f2bf(a0 - bf2f(h0)), l1 = f2bf(a1 - bf2f(h1));
                *(unsigned*)(void*)&AlS[mm * 40 + kp * 2] = ((unsigned)l1 << 16) | (unsigned)l0;
            }
        }
        {
            int n = tid >> 2, seg = tid & 3;
            size_t gb = (size_t)(n0 + n) * K + kb + seg * 8;
            *(sh8*)(void*)&BhS[n * 40 + seg * 8] = *(const sh8*)(const void*)&Bh[gb];
            if (SPLIT) *(sh8*)(void*)&BlS[n * 40 + seg * 8] = *(const sh8*)(const void*)&Bl[gb];
        }
        __syncthreads();
        sh8 af[4], bf[2], afl[4], bfl[2];
        #pragma unroll
        for (int mt = 0; mt < 4; mt++) {
            af[mt] = *(const sh8*)(const void*)&AhS[(wm + mt * 16 + l15) * 40 + lk];
            if (SPLIT) afl[mt] = *(const sh8*)(const void*)&AlS[(wm + mt * 16 + l15) * 40 + lk];
        }
        #pragma unroll
        for (int nt = 0; nt < 2; nt++) {
            bf[nt] = *(const sh8*)(const void*)&BhS[(wn + nt * 16 + l15) * 40 + lk];
            if (SPLIT) bfl[nt] = *(const sh8*)(const void*)&BlS[(wn + nt * 16 + l15) * 40 + lk];
        }
        #pragma unroll
        for (int mt = 0; mt < 4; mt++)
            #pragma unroll
            for (int nt = 0; nt < 2; nt++) {
                acc[mt][nt] = __builtin_amdgcn_mfma_f32_16x16x32_bf16(af[mt], bf[nt], acc[mt][nt], 0, 0, 0);
                if (SPLIT) {
                    acc[mt][nt] = __builtin_amdgcn_mfma_f32_16x16x32_bf16(af[mt], bfl[nt], acc[mt][nt], 0, 0, 0);
                    acc[mt][nt] = __builtin_amdgcn_mfma_f32_16x16x32_bf16(afl[mt], bf[nt], acc[mt][nt], 0, 0, 0);
                }
            }
        __syncthreads();
    }
    #pragma unroll
    for (int nt = 0; nt < 2; nt++) {
        int n = n0 + wn + nt * 16 + l15;
        float bs = bias[n];
        #pragma unroll
        for (int mt = 0; mt < 4; mt++) {
            int mloc = m0 + wm + mt * 16 + lk4;
            float4 v;
            float* vp = (float*)&v;
            #pragma unroll
            for (int r = 0; r < 4; r++) {
                float q = acc[mt][nt][r] + bs;
                if (LRELU) q = (q < 0.f) ? 0.1f * q : q;
                vp[r] = q;
            }
            *(float4*)&C[(size_t)n * M + mloc] = v;
        }
    }
}

// ---------------------------------------------------------------- fp32 GEMM (R3-verified), for u2/u4 resize-fused
template<int BMODE>
__global__ __launch_bounds__(256) void k_gemm(const float* __restrict__ A, int lda,
                                              const float* __restrict__ B,
                                              const float* __restrict__ bias,
                                              float* __restrict__ C,
                                              int N, int K,
                                              int wshift, int srcH, int srcW, int flags) {
    __shared__ float As[8][64];
    __shared__ float Bs[8][256];
    int tid = threadIdx.x;
    int tx = tid & 31, ty = tid >> 5;
    int n0 = blockIdx.x * 256;
    int m0 = blockIdx.y * 64;
    float acc[8][8] = {};
    for (int kb = 0; kb < K; kb += 8) {
        #pragma unroll
        for (int e = 0; e < 2; e++) {
            int i = e * 256 + tid;
            int mm = i & 63, kk = i >> 6;
            As[kk][mm] = A[(size_t)(m0 + mm) * lda + kb + kk];
        }
        #pragma unroll
        for (int e = 0; e < 8; e++) {
            int i = e * 256 + tid;
            int nn = i & 255, kk = i >> 8;
            int k = kb + kk, n = n0 + nn;
            float v = 0.f;
            if (BMODE == 0) {
                if (n < N) v = B[(size_t)k * N + n];
            } else {
                int jj = n & ((1 << wshift) - 1), ii = n >> wshift;
                const float* p = B + (size_t)k * srcH * srcW;
                int ky = ii >> 1, ylo, yhi; float wyl, wyh;
                if ((ii & 1) == 0) { ylo = ky - 1; yhi = ky; wyl = .25f; wyh = .75f; if (ylo < 0) { ylo = 0; wyl = 0.f; wyh = 1.f; } }
                else               { ylo = ky; yhi = ky + 1; wyl = .75f; wyh = .25f; if (yhi > srcH - 1) { yhi = srcH - 1; wyh = 0.f; wyl = 1.f; } }
                int kx = jj >> 1, xlo, xhi; float wxl, wxh;
                if ((jj & 1) == 0) { xlo = kx - 1; xhi = kx; wxl = .25f; wxh = .75f; if (xlo < 0) { xlo = 0; wxl = 0.f; wxh = 1.f; } }
                else               { xlo = kx; xhi = kx + 1; wxl = .75f; wxh = .25f; if (xhi > srcW - 1) { xhi = srcW - 1; wxh = 0.f; wxl = 1.f; } }
                v = wyl * (wxl * p[(size_t)ylo * srcW + xlo] + wxh * p[(size_t)ylo * srcW + xhi]) +
                    wyh * (wxl * p[(size_t)yhi * srcW + xlo] + wxh * p[(size_t)yhi * srcW + xhi]);
            }
            Bs[kk][nn] = v;
        }
        __syncthreads();
        #pragma unroll
        for (int kk = 0; kk < 8; kk++) {
            float4 A0 = *(const float4*)&As[kk][ty * 8];
            float4 A1 = *(const float4*)&As[kk][ty * 8 + 4];
            float4 B0 = *(const float4*)&Bs[kk][tx * 4];
            float4 B1 = *(const float4*)&Bs[kk][128 + tx * 4];
            float av[8] = {A0.x, A0.y, A0.z, A0.w, A1.x, A1.y, A1.z, A1.w};
            float bv[8] = {B0.x, B0.y, B0.z, B0.w, B1.x, B1.y, B1.z, B1.w};
            #pragma unroll
            for (int r = 0; r < 8; r++)
                #pragma unroll
                for (int s = 0; s < 8; s++)
                    acc[r][s] += av[r] * bv[s];
        }
        __syncthreads();
    }
    int n1 = n0 + tx * 4, n2 = n0 + 128 + tx * 4;
    #pragma unroll
    for (int r = 0; r < 8; r++) {
        int m = m0 + ty * 8 + r;
        float bs = bias ? bias[m] : 0.f;
        float o[8];
        #pragma unroll
        for (int s = 0; s < 8; s++) {
            float v = acc[r][s] + bs;
            if (flags & 1) v = (v < 0.f) ? 0.1f * v : v;
            o[s] = v;
        }
        size_t rowb = (size_t)m * N;
        if (n1 < N) *(float4*)&C[rowb + n1] = make_float4(o[0], o[1], o[2], o[3]);
        if (n2 < N) *(float4*)&C[rowb + n2] = make_float4(o[4], o[5], o[6], o[7]);
    }
}

// ---------------------------------------------------------------- amp = sqrt(re^2+im^2), layout -> [c][t][kf]
__global__ __launch_bounds__(128) void k_ampc(const float* __restrict__ F2C, float* __restrict__ ampb) {
    int bid = blockIdx.x;          // c*128 + t
    int kf = threadIdx.x;
    if (kf >= 65) return;
    int c = bid >> 7, t = bid & 127;
    size_t m = (size_t)c * 65 + kf;
    float re = F2C[(size_t)t * 16640 + m];
    float im = F2C[(size_t)(t + 128) * 16640 + m];
    ampb[(size_t)bid * 65 + kf] = sqrtf(re * re + im * im);
}

// ---------------------------------------------------------------- z = a*(cos a, sin a) -> stacked [t][(c,kf)] planes
__global__ __launch_bounds__(128) void k_zbuild(const float* __restrict__ A2, float* __restrict__ Z) {
    int bid = blockIdx.x;          // c*128 + t
    int kf = threadIdx.x;
    if (kf >= 65) return;
    int c = bid >> 7, t = bid & 127;
    float a = A2[(size_t)bid * 65 + kf];
    float s_, c_;
    sincosf(a, &s_, &c_);
    size_t m = (size_t)c * 65 + kf;
    Z[(size_t)t * 16640 + m] = a * c_;
    Z[2129920 + (size_t)t * 16640 + m] = a * s_;
}

// ---------------------------------------------------------------- h3 = Wc[:, :64] @ g2 (channels-first)
__global__ __launch_bounds__(256) void k_h3(const float* __restrict__ g2, const float* __restrict__ Wc,
                                            float* __restrict__ h3) {
    __shared__ float wa[192];
    int tid = threadIdx.x;
    if (tid < 192) { int r = tid >> 6, c = tid & 63; wa[tid] = Wc[r * 128 + c]; }
    __syncthreads();
    int q = blockIdx.x * 256 + tid;
    float a0 = 0.f, a1 = 0.f, a2 = 0.f;
    #pragma unroll 4
    for (int c = 0; c < 64; c++) {
        float v = g2[(size_t)c * 65536 + q];
        a0 += wa[c] * v;
        a1 += wa[64 + c] * v;
        a2 += wa[128 + c] * v;
    }
    h3[q] = a0; h3[65536 + q] = a1; h3[131072 + q] = a2;
}

// ---------------------------------------------------------------- final fused stage @512^2 (R3-verified)
__global__ __launch_bounds__(256) void k_final(const float* __restrict__ x,
                                               const float* __restrict__ dark, const int* __restrict__ gmax,
                                               const float* __restrict__ wcf1, const float* __restrict__ bcf1,
                                               const float* __restrict__ Wc, const float* __restrict__ bc,
                                               const float* __restrict__ g4, const float* __restrict__ h3,
                                               float* __restrict__ out) {
    __shared__ float dimt[32], w1[192], b1[64], wb[192], bcs[3];
    int tid = threadIdx.x;
    if (tid < 32) dimt[tid] = powf(10000.f, (float)(2 * (tid >> 1)) / 32.f);
    if (tid < 192) w1[tid] = wcf1[tid];
    if (tid < 64) b1[tid] = bcf1[tid];
    if (tid < 192) { int r = tid / 64, c = tid - (tid / 64) * 64; wb[tid] = Wc[r * 128 + 64 + c]; }
    if (tid < 3) bcs[tid] = bc[tid];
    __syncthreads();
    int p = blockIdx.x * 256 + tid;
    int i = p >> 9, j = p & 511;
    const float scale = 2.f * PI_F;
    float inv511 = scale / (511.f + 1e-6f);
    float xe = (float)j * inv511, ye = (float)i * inv511;
    float gm = __int_as_float(gmax[0]);
    float ze = dark[p] / (gm + 1e-6f) * scale;
    float x0 = x[p], x1 = x[p + NPIX], x2 = x[p + 2 * NPIX];

    int ky = i >> 1, ylo, yhi; float wyl, wyh;
    if ((i & 1) == 0) { ylo = ky - 1; yhi = ky; wyl = .25f; wyh = .75f; if (ylo < 0) { ylo = 0; wyl = 0.f; wyh = 1.f; } }
    else              { ylo = ky; yhi = ky + 1; wyl = .75f; wyh = .25f; if (yhi > 255) { yhi = 255; wyh = 0.f; wyl = 1.f; } }
    int kx = j >> 1, xlo, xhi; float wxl, wxh;
    if ((j & 1) == 0) { xlo = kx - 1; xhi = kx; wxl = .25f; wxh = .75f; if (xlo < 0) { xlo = 0; wxl = 0.f; wxh = 1.f; } }
    else              { xlo = kx; xhi = kx + 1; wxl = .75f; wxh = .25f; if (xhi > 255) { xhi = 255; wxh = 0.f; wxl = 1.f; } }
    int s00 = ylo * 256 + xlo, s01 = ylo * 256 + xhi, s10 = yhi * 256 + xlo, s11 = yhi * 256 + xhi;
    float w00 = wyl * wxl, w01 = wyl * wxh, w10 = wyh * wxl, w11 = wyh * wxh;

    float a0 = 0.f, a1 = 0.f, a2 = 0.f;
    #pragma unroll 1
    for (int c = 0; c < 64; c++) {
        float e = (c < 16) ? xe / dimt[c] : (c < 32) ? ye / dimt[c - 16] : ze / dimt[c - 32];
        float sn, cs;
        __sincosf(e, &sn, &cs);
        float pos = ((c & 1) == 0) ? sn : cs;
        float ape = pos + w1[c * 3] * x0 + w1[c * 3 + 1] * x1 + w1[c * 3 + 2] * x2 + b1[c];
        const float* gp = g4 + (size_t)c * 65536;
        float gv = w00 * gp[s00] + w01 * gp[s01] + w10 * gp[s10] + w11 * gp[s11];
        float s = gv * ape;
        a0 += wb[c] * s; a1 += wb[64 + c] * s; a2 += wb[128 + c] * s;
    }
    float f0 = w00 * h3[s00] + w01 * h3[s01] + w10 * h3[s10] + w11 * h3[s11];
    const float* h1 = h3 + 65536;
    float f1 = w00 * h1[s00] + w01 * h1[s01] + w10 * h1[s10] + w11 * h1[s11];
    const float* h2 = h3 + 131072;
    float f2 = w00 * h2[s00] + w01 * h2[s01] + w10 * h2[s10] + w11 * h2[s11];
    out[p]            = a0 + f0 + bcs[0] + x0;
    out[NPIX + p]     = a1 + f1 + bcs[1] + x1;
    out[2 * NPIX + p] = a2 + f2 + bcs[2] + x2;
}

// ================================================================ launcher
extern "C" void kernel_launch(void* const* d_in, const int* in_sizes, int n_in,
                              void* d_out, int out_size, void* d_ws, size_t ws_size,
                              hipStream_t stream) {
    const float* x      = (const float*)d_in[0];
    const float* w_cf1  = (const float*)d_in[1];  const float* b_cf1 = (const float*)d_in[2];
    const float* w_e1   = (const float*)d_in[3];  const float* b_e1  = (const float*)d_in[4];
    const float* w_e2   = (const float*)d_in[5];  const float* b_e2  = (const float*)d_in[6];
    const float* w_d1   = (const float*)d_in[7];  const float* b_d1  = (const float*)d_in[8];
    const float* w_d2   = (const float*)d_in[9];  const float* b_d2  = (const float*)d_in[10];
    // 11..14: pha branch is dead code in the reference
    const float* w_amp1 = (const float*)d_in[15]; const float* b_amp1 = (const float*)d_in[16];
    const float* w_amp2 = (const float*)d_in[17]; const float* b_amp2 = (const float*)d_in[18];
    const float* w_sp1  = (const float*)d_in[19]; const float* b_sp1  = (const float*)d_in[20];
    const float* w_sp2  = (const float*)d_in[21]; const float* b_sp2  = (const float*)d_in[22];
    const float* w_u1   = (const float*)d_in[23]; const float* b_u1   = (const float*)d_in[24];
    const float* w_u2   = (const float*)d_in[25]; const float* b_u2   = (const float*)d_in[26];
    const float* w_u3   = (const float*)d_in[27]; const float* b_u3   = (const float*)d_in[28];
    const float* w_u4   = (const float*)d_in[29]; const float* b_u4   = (const float*)d_in[30];
    const float* w_cf2  = (const float*)d_in[31]; const float* b_cf2  = (const float*)d_in[32];
    const float* w_cf3  = (const float*)d_in[33]; const float* b_cf3  = (const float*)d_in[34];
    float* out = (float*)d_out;

    char* ws = (char*)d_ws;
    constexpr size_t MiB = 1ull << 20;
    float*  dark   = (float*)(ws + 0 * MiB);
    float*  tmp    = (float*)(ws + 1 * MiB);
    int*    gmax   = (int*)  (ws + 2 * MiB);
    float*  Wc     = (float*)(ws + 2 * MiB + 1024);
    float*  bc     = (float*)(ws + 2 * MiB + 1024 + 1536);
    float*  xf     = (float*)(ws + 3 * MiB);     // [3,67)
    float*  xd1    = (float*)(ws + 67 * MiB);    // [67,99)
    float*  xd2    = (float*)(ws + 99 * MiB);    // [99,115) live until sp1
    float*  F1C    = (float*)(ws + 115 * MiB);   // 32    [115,147)
    float*  F2C    = (float*)(ws + 147 * MiB);   // 16.25 [147,163.25)
    float*  ampb   = (float*)(ws + 164 * MiB);   // 8.125 [164,172.125)
    float*  A1     = (float*)(ws + 173 * MiB);   // 8.125 [173,181.125)
    float*  A2     = (float*)(ws + 182 * MiB);   // 8.125 [182,190.125)
    float*  Zbuf   = (float*)(ws + 115 * MiB);   // 16.25 (F1C dead after F2)
    float*  I1C    = (float*)(ws + 132 * MiB);   // 16.25+pad [132,149) (F1C tail dead)
    float*  I2C    = (float*)(ws + 149 * MiB);   // 16    [149,165) (F2C/ampb dead)
    float*  g1out  = (float*)(ws + 3 * MiB);     // xf dead after d1
    float*  g2out  = (float*)(ws + 11 * MiB);    // [11,27)
    float*  h3     = (float*)(ws + 27 * MiB);
    float*  s1     = (float*)(ws + 31 * MiB);    // [31,47)
    float*  s2     = (float*)(ws + 47 * MiB);    // [47,63)
    float*  g3out  = (float*)(ws + 63 * MiB);    // [63,71) (xd1 dead)
    float*  g4out  = (float*)(ws + 71 * MiB);    // [71,87)
    unsigned short* wb16 = (unsigned short*)(ws + 192 * MiB);  // [192,196)
    unsigned short* d1h = wb16 + 0,       * d1l = wb16 + 32768;
    unsigned short* d2h = wb16 + 65536,   * d2l = wb16 + 196608;
    unsigned short* a1h = wb16 + 327680,  * a1l = wb16 + 393216;
    unsigned short* a2h = wb16 + 458752,  * a2l = wb16 + 524288;
    unsigned short* s1h = wb16 + 589824;
    unsigned short* s2h = wb16 + 655360;
    unsigned short* u1h = wb16 + 720896;
    unsigned short* u3h = wb16 + 753664;
    unsigned short* BfH = wb16 + 786432,  * BfL = wb16 + 819200;
    unsigned short* BfcH = wb16 + 851968, * BfcL = wb16 + 917504;
    unsigned short* BicH = wb16 + 983040, * BicL = wb16 + 1048576;
    unsigned short* BirH = wb16 + 1114112,* BirL = wb16 + 1134592;  // ends 1155072 shorts
    float* zbias = (float*)(ws + 195 * MiB + 512 * 1024);

    // 1) dark channel + gmax + composed cf weights + weight/B prep
    k_minc<<<1024, 256, 0, stream>>>(x, dark, gmax);
    k_minrow<<<1024, 256, 0, stream>>>(dark, tmp);
    k_mincol_max<<<1024, 256, 0, stream>>>(tmp, dark, gmax);
    k_wc<<<1, 128, 0, stream>>>(w_cf2, b_cf2, w_cf3, b_cf3, Wc, bc);
    k_prepw<<<128, 256, 0, stream>>>(w_d1, d1h, d1l, 128, 256, 6);
    k_prepw<<<512, 256, 0, stream>>>(w_d2, d2h, d2l, 256, 512, 7);
    k_prepw<<<256, 256, 0, stream>>>(w_amp1, a1h, a1l, 256, 256, 0);
    k_prepw<<<256, 256, 0, stream>>>(w_amp2, a2h, a2l, 256, 256, 0);
    k_prepw<<<256, 256, 0, stream>>>(w_sp1, s1h, nullptr, 256, 256, 0);
    k_prepw<<<256, 256, 0, stream>>>(w_sp2, s2h, nullptr, 256, 256, 0);
    k_prepw<<<128, 256, 0, stream>>>(w_u1, u1h, nullptr, 128, 256, 0);
    k_prepw<<<128, 256, 0, stream>>>(w_u3, u3h, nullptr, 128, 256, 0);
    k_bfft<<<720, 256, 0, stream>>>(BfH, BfL, BfcH, BfcL, BicH, BicL, BirH, BirL, zbias);

    // 2) x_f channels-first
    k_ef<<<1024, 256, 0, stream>>>(x, w_e1, b_e1, w_e2, b_e2, xf);

    // 3) d1/d2 (MFMA split, s2d)
    k_mmcf<1, 1, 0><<<dim3(512, 2), 256, 0, stream>>>(xf, d1h, d1l, b_d1, xd1, 65536, 128, 256, 6, 8, 512);
    k_mmcf<1, 1, 0><<<dim3(128, 4), 256, 0, stream>>>(xd1, d2h, d2l, b_d2, xd2, 16384, 256, 512, 7, 7, 256);

    // 4) FFT section as MFMA GEMMs (split-bf16 DFT matrices)
    // F1: row rfft -> F1C [re(128)|im(128)][c*128+row]
    k_mmcf<3, 1, 0><<<dim3(256, 4), 256, 0, stream>>>(xd2, BfH, BfL, zbias, F1C, 32768, 256, 128, 0, 0, 0);
    // F2: col fft -> F2C [re_t(128)|im_t(128)][c*65+kf]
    k_mmcf<4, 1, 0><<<dim3(130, 4), 256, 0, stream>>>(F1C, BfcH, BfcL, zbias, F2C, 16640, 256, 256, 0, 0, 0);
    // amp combine -> ampb [c][t][kf]
    k_ampc<<<32768, 128, 0, stream>>>(F2C, ampb);
    // amp MLP (verified)
    k_mmcf<0, 1, 1><<<dim3(65, 4), 256, 0, stream>>>(ampb, a1h, a1l, b_amp1, A1, 8320, 256, 256, 0, 0, 0);
    k_mmcf<0, 1, 0><<<dim3(65, 4), 256, 0, stream>>>(A1, a2h, a2l, b_amp2, A2, 8320, 256, 256, 0, 0, 0);
    // z build -> Zbuf stacked [t][c*65+kf] re|im
    k_zbuild<<<32768, 128, 0, stream>>>(A2, Zbuf);
    // I1: inverse col -> I1C [re_tau(128)|im_tau(128)][c*65+kf]
    k_mmcf<0, 1, 0><<<dim3(130, 4), 256, 0, stream>>>(Zbuf, BicH, BicL, zbias, I1C, 16640, 256, 256, 0, 0, 0);
    // I2: inverse row c2r -> I2C [col][c*128+tau]
    k_mmcf<5, 1, 0><<<dim3(256, 2), 256, 0, stream>>>(I1C, BirH, BirL, zbias, I2C, 32768, 128, 160, 0, 0, 0);

    // 5) four path: u1 (MFMA, gathers I2C layout) ; u2 fp32 fused-resize ; h3
    k_mmcf<6, 0, 0><<<dim3(128, 2), 256, 0, stream>>>(I2C, u1h, nullptr, b_u1, g1out, 16384, 128, 256, 0, 0, 0);
    k_gemm<2><<<dim3(256, 1), 256, 0, stream>>>(w_u2, 128, g1out, b_u2, g2out, 65536, 128, 8, 128, 128, 0);
    k_h3<<<256, 256, 0, stream>>>(g2out, Wc, h3);

    // 6) spat path
    k_mmcf<0, 0, 1><<<dim3(128, 4), 256, 0, stream>>>(xd2, s1h, nullptr, b_sp1, s1, 16384, 256, 256, 0, 0, 0);
    k_mmcf<0, 0, 0><<<dim3(128, 4), 256, 0, stream>>>(s1, s2h, nullptr, b_sp2, s2, 16384, 256, 256, 0, 0, 0);
    k_mmcf<0, 0, 0><<<dim3(128, 2), 256, 0, stream>>>(s2, u3h, nullptr, b_u3, g3out, 16384, 128, 256, 0, 0, 0);
    k_gemm<2><<<dim3(256, 1), 256, 0, stream>>>(w_u4, 128, g3out, b_u4, g4out, 65536, 128, 8, 128, 128, 0);

    // 7) final fused stage
    k_final<<<1024, 256, 0, stream>>>(x, dark, gmax, w_cf1, b_cf1, Wc, bc, g4out, h3, out);
}

// Round 9
// 606.281 us; speedup vs baseline: 2.8049x; 1.2007x over previous
//
#include <hip/hip_runtime.h>
#include <math.h>

#define PI_F 3.14159265358979323846f
#define NPIX 262144   // 512*512

typedef __attribute__((ext_vector_type(8))) short sh8;
typedef __attribute__((ext_vector_type(4))) float fx4;

__device__ __forceinline__ unsigned short f2bf(float v) {
    unsigned u = __float_as_uint(v);
    return (unsigned short)((u + 0x7FFFu + ((u >> 16) & 1)) >> 16);
}
__device__ __forceinline__ float bf2f(unsigned short h) {
    return __uint_as_float((unsigned)h << 16);
}

// ---------------------------------------------------------------- dark channel
__global__ __launch_bounds__(256) void k_minc(const float* __restrict__ x, float* __restrict__ dm,
                                              int* __restrict__ gmax) {
    int p = blockIdx.x * 256 + threadIdx.x;
    if (p == 0) gmax[0] = 0;
    float m = fmaxf(x[p], fmaxf(x[p + NPIX], x[p + 2 * NPIX]));
    dm[p] = 1.0f - m;
}

__device__ __forceinline__ int refl512(int t) {
    if (t < 0) t = -t;
    if (t > 511) t = 1022 - t;
    return t;
}

__global__ __launch_bounds__(256) void k_minrow(const float* __restrict__ dm, float* __restrict__ tmp) {
    int p = blockIdx.x * 256 + threadIdx.x;
    int i = p >> 9, j = p & 511;
    float m = 1e30f;
    #pragma unroll
    for (int d = -7; d <= 7; d++) m = fminf(m, dm[(i << 9) + refl512(j + d)]);
    tmp[p] = m;
}

__global__ __launch_bounds__(256) void k_mincol_max(const float* __restrict__ tmp, float* __restrict__ dark,
                                                    int* __restrict__ gmax) {
    int p = blockIdx.x * 256 + threadIdx.x;
    int i = p >> 9, j = p & 511;
    float m = 1e30f;
    #pragma unroll
    for (int d = -7; d <= 7; d++) m = fminf(m, tmp[(refl512(i + d) << 9) + j]);
    dark[p] = m;
    __shared__ float red[256];
    int tid = threadIdx.x;
    red[tid] = m;
    __syncthreads();
    for (int s = 128; s > 0; s >>= 1) {
        if (tid < s) red[tid] = fmaxf(red[tid], red[tid + s]);
        __syncthreads();
    }
    if (tid == 0) atomicMax(gmax, __float_as_int(red[0]));
}

// ---------------------------------------------------------------- composed weights:
// Wc = w_cf3 @ w_cf2 (3x128), bc ; W2c = Wc[:, :64] @ w_u2 (3x128), b2c = Wc[:, :64] @ b_u2
__global__ __launch_bounds__(128) void k_wc(const float* __restrict__ w2, const float* __restrict__ b2,
                                            const float* __restrict__ w3, const float* __restrict__ b3,
                                            const float* __restrict__ wu2, const float* __restrict__ bu2,
                                            float* __restrict__ Wc, float* __restrict__ bc,
                                            float* __restrict__ W2c, float* __restrict__ b2c) {
    __shared__ float sWc[3 * 128];
    int j = threadIdx.x;
    for (int r = 0; r < 3; r++) {
        float s = 0.f;
        for (int o = 0; o < 64; o++) s += w3[r * 64 + o] * w2[o * 128 + j];
        sWc[r * 128 + j] = s;
        Wc[r * 128 + j] = s;
    }
    if (j < 3) {
        float s = b3[j];
        for (int o = 0; o < 64; o++) s += w3[j * 64 + o] * b2[o];
        bc[j] = s;
    }
    __syncthreads();
    for (int r = 0; r < 3; r++) {
        float s = 0.f;
        for (int o = 0; o < 64; o++) s += sWc[r * 128 + o] * wu2[o * 128 + j];
        W2c[r * 128 + j] = s;
    }
    if (j < 3) {
        float s = 0.f;
        for (int o = 0; o < 64; o++) s += sWc[j * 128 + o] * bu2[o];
        b2c[j] = s;
    }
}

// ---------------------------------------------------------------- weight prep
__global__ __launch_bounds__(256) void k_prepw(const float* __restrict__ w, unsigned short* __restrict__ h,
                                               unsigned short* __restrict__ l, int N, int K, int cshift) {
    int idx = blockIdx.x * 256 + threadIdx.x;
    if (idx >= N * K) return;
    int n = idx / K, kord = idx - n * K;
    int ksrc = kord;
    if (cshift) {
        int dydx = kord >> cshift, c = kord & ((1 << cshift) - 1);
        ksrc = c * 4 + dydx;
    }
    float v = w[n * K + ksrc];
    unsigned short hb = f2bf(v);
    h[idx] = hb;
    if (l) l[idx] = f2bf(v - bf2f(hb));
}

// ---------------------------------------------------------------- DFT B-matrix builder (split bf16, exact mod-128 angles)
__global__ __launch_bounds__(256) void k_bfft(unsigned short* __restrict__ BfH, unsigned short* __restrict__ BfL,
                                              unsigned short* __restrict__ BfcH, unsigned short* __restrict__ BfcL,
                                              unsigned short* __restrict__ BicH, unsigned short* __restrict__ BicL,
                                              unsigned short* __restrict__ BirH, unsigned short* __restrict__ BirL,
                                              float* __restrict__ zbias) {
    int idx = blockIdx.x * 256 + threadIdx.x;
    if (idx < 256) zbias[idx] = 0.f;
    const float w0 = 2.f * PI_F / 128.f;
    float v;
    unsigned short *H, *L;
    int off;
    if (idx < 32768) {                     // Bf [256][128]
        int n = idx >> 7, k = idx & 127;
        int t = n & 127, r = (t * k) & 127;
        float s_, c_; sincosf(w0 * r, &s_, &c_);
        v = (n < 128) ? c_ : -s_;
        H = BfH; L = BfL; off = idx;
    } else if (idx < 98304) {              // Bfc [256][256]
        int i = idx - 32768;
        int n = i >> 8, j = i & 255;
        int t = n & 127, r = (t * (j & 127)) & 127;
        float s_, c_; sincosf(w0 * r, &s_, &c_);
        v = (n < 128) ? ((j < 128) ? c_ : s_) : ((j < 128) ? -s_ : c_);
        H = BfcH; L = BfcL; off = i;
    } else if (idx < 163840) {             // Bic [256][256]
        int i = idx - 98304;
        int n = i >> 8, j = i & 255;
        int t = n & 127, r = (t * (j & 127)) & 127;
        float s_, c_; sincosf(w0 * r, &s_, &c_);
        v = ((n < 128) ? ((j < 128) ? c_ : -s_) : ((j < 128) ? s_ : c_)) * (1.f / 128.f);
        H = BicH; L = BicL; off = i;
    } else if (idx < 184320) {             // Bir [128][160]
        int i = idx - 163840;
        int col = i / 160, j = i - col * 160;
        if (j == 0) v = 1.f / 128.f;
        else if (j < 64)  { int r = (j * col) & 127; float s_, c_; sincosf(w0 * r, &s_, &c_); v = 2.f * c_ / 128.f; }
        else if (j == 64) v = (col & 1) ? -1.f / 128.f : 1.f / 128.f;
        else if (j >= 66 && j <= 128) { int k = j - 65; int r = (k * col) & 127; float s_, c_; sincosf(w0 * r, &s_, &c_); v = -2.f * s_ / 128.f; }
        else v = 0.f;
        H = BirH; L = BirL; off = i;
    } else return;
    unsigned short hb = f2bf(v);
    H[off] = hb;
    L[off] = f2bf(v - bf2f(hb));
}

// ---------------------------------------------------------------- x_f = e2(e1(x)), channels-first
__global__ __launch_bounds__(256) void k_ef(const float* __restrict__ x,
                                            const float* __restrict__ w1, const float* __restrict__ b1,
                                            const float* __restrict__ w2, const float* __restrict__ b2,
                                            float* __restrict__ out) {
    __shared__ float sw1[24], sb1[8], sw2[512], sb2[64];
    int tid = threadIdx.x;
    if (tid < 24) sw1[tid] = w1[tid];
    if (tid < 8)  sb1[tid] = b1[tid];
    if (tid < 64) sb2[tid] = b2[tid];
    if (tid < 256) { sw2[tid] = w2[tid]; sw2[tid + 256] = w2[tid + 256]; }
    __syncthreads();
    int p = blockIdx.x * 256 + tid;
    float x0 = x[p], x1 = x[p + NPIX], x2 = x[p + 2 * NPIX];
    float h[8];
    #pragma unroll
    for (int r = 0; r < 8; r++)
        h[r] = sw1[r * 3] * x0 + sw1[r * 3 + 1] * x1 + sw1[r * 3 + 2] * x2 + sb1[r];
    #pragma unroll 1
    for (int o = 0; o < 64; o++) {
        float acc = sb2[o];
        #pragma unroll
        for (int r = 0; r < 8; r++) acc += sw2[o * 8 + r] * h[r];
        out[(size_t)o * NPIX + p] = acc;
    }
}

// ---------------------------------------------------------------- channels-first MFMA GEMM (R7-verified core)
// C[n][M+m] = sum_k B[n][k] * A(k, m) + bias[n]
// AMODE 0: A[k][m] row-major [K][M]
// AMODE 1: s2d gather from channels-first src
// AMODE 3: A[m][K] row-major (lda = K)
// AMODE 4: F2 col-fwd gather
// AMODE 5: I2 c2r gather
// AMODE 6: u1 gather from I2 output
template<int AMODE, int SPLIT, int LRELU>
__global__ __launch_bounds__(256) void k_mmcf(const float* __restrict__ Asrc,
                                              const unsigned short* __restrict__ Bh,
                                              const unsigned short* __restrict__ Bl,
                                              const float* __restrict__ bias, float* __restrict__ C,
                                              int M, int N, int K, int cshift, int wshift, int srcW) {
    __shared__ unsigned short AhS[128 * 40];
    __shared__ unsigned short BhS[64 * 40];
    __shared__ unsigned short AlS[SPLIT ? 128 * 40 : 8];
    __shared__ unsigned short BlS[SPLIT ? 64 * 40 : 8];
    int tid = threadIdx.x;
    int m0 = blockIdx.x * 128;
    int n0 = blockIdx.y * 64;
    int wave = tid >> 6, lane = tid & 63;
    int wm = (wave >> 1) * 64, wn = (wave & 1) * 32;
    int l15 = lane & 15, quad = lane >> 4;
    int lk = quad * 8, lk4 = quad * 4;
    fx4 acc[4][2];
    #pragma unroll
    for (int a = 0; a < 4; a++)
        #pragma unroll
        for (int b = 0; b < 2; b++)
            acc[a][b] = (fx4){0.f, 0.f, 0.f, 0.f};

    int mm = tid & 127;
    int kpb = tid >> 7;          // 0/1
    int gm = m0 + mm;
    int oj = 0, oi = 0;
    size_t abase = 0;
    if (AMODE == 1) { oj = gm & ((1 << wshift) - 1); oi = gm >> wshift; }
    if (AMODE == 3) { abase = (size_t)gm * K; }
    if (AMODE == 4) { int c = gm / 65, kf = gm - c * 65; abase = (size_t)kf * 32768 + (size_t)c * 128; }
    if (AMODE == 5) { abase = (size_t)(gm & 127) * 16640 + (size_t)(gm >> 7) * 65; }
    if (AMODE == 6) { abase = (size_t)(gm & 127) * 32768 + (size_t)(gm >> 7); }

    for (int kb = 0; kb < K; kb += 32) {
        #pragma unroll
        for (int t = 0; t < 8; t++) {
            int kp = kpb + t * 2;          // [0,16)
            int k0 = kb + kp * 2;
            float a0, a1;
            if (AMODE == 0) {
                a0 = Asrc[(size_t)k0 * M + gm];
                a1 = Asrc[(size_t)(k0 + 1) * M + gm];
            } else if (AMODE == 1) {
                int c = k0 & ((1 << cshift) - 1);
                int dydx = k0 >> cshift;
                int dy = dydx >> 1, dx = dydx & 1;
                size_t pix = (size_t)(2 * oi + dy) * srcW + (2 * oj + dx);
                size_t plane = (size_t)srcW * srcW;
                a0 = Asrc[(size_t)c * plane + pix];
                a1 = Asrc[(size_t)(c + 1) * plane + pix];
            } else if (AMODE == 3) {
                a0 = Asrc[abase + k0];
                a1 = Asrc[abase + k0 + 1];
            } else if (AMODE == 4) {
                int j0 = k0, j1 = k0 + 1;
                a0 = Asrc[abase + (j0 < 128 ? j0 : 4194304 + (j0 - 128))];
                a1 = Asrc[abase + (j1 < 128 ? j1 : 4194304 + (j1 - 128))];
            } else if (AMODE == 5) {
                int j0 = k0, j1 = k0 + 1;
                a0 = Asrc[abase + (j0 < 65 ? j0 : 2129920 + (j0 - 65))];
                a1 = Asrc[abase + (j1 < 65 ? j1 : 2129920 + (j1 - 65))];
            } else {
                a0 = Asrc[abase + (size_t)k0 * 128];
                a1 = Asrc[abase + (size_t)(k0 + 1) * 128];
            }
            unsigned short h0 = f2bf(a0), h1 = f2bf(a1);
            *(unsigned*)(void*)&AhS[mm * 40 + kp * 2] = ((unsigned)h1 << 16) | (unsigned)h0;
            if (SPLIT) {
                unsigned short l0 = f2bf(a0 - bf2f(h0)), l1 = f2bf(a1 - bf2f(h1));
                *(unsigned*)(void*)&AlS[mm * 40 + kp * 2] = ((unsigned)l1 << 16) | (unsigned)l0;
            }
        }
        {
            int n = tid >> 2, seg = tid & 3;
            size_t gb = (size_t)(n0 + n) * K + kb + seg * 8;
            *(sh8*)(void*)&BhS[n * 40 + seg * 8] = *(const sh8*)(const void*)&Bh[gb];
            if (SPLIT) *(sh8*)(void*)&BlS[n * 40 + seg * 8] = *(const sh8*)(const void*)&Bl[gb];
        }
        __syncthreads();
        sh8 af[4], bf[2], afl[4], bfl[2];
        #pragma unroll
        for (int mt = 0; mt < 4; mt++) {
            af[mt] = *(const sh8*)(const void*)&AhS[(wm + mt * 16 + l15) * 40 + lk];
            if (SPLIT) afl[mt] = *(const sh8*)(const void*)&AlS[(wm + mt * 16 + l15) * 40 + lk];
        }
        #pragma unroll
        for (int nt = 0; nt < 2; nt++) {
            bf[nt] = *(const sh8*)(const void*)&BhS[(wn + nt * 16 + l15) * 40 + lk];
            if (SPLIT) bfl[nt] = *(const sh8*)(const void*)&BlS[(wn + nt * 16 + l15) * 40 + lk];
        }
        #pragma unroll
        for (int mt = 0; mt < 4; mt++)
            #pragma unroll
            for (int nt = 0; nt < 2; nt++) {
                acc[mt][nt] = __builtin_amdgcn_mfma_f32_16x16x32_bf16(af[mt], bf[nt], acc[mt][nt], 0, 0, 0);
                if (SPLIT) {
                    acc[mt][nt] = __builtin_amdgcn_mfma_f32_16x16x32_bf16(af[mt], bfl[nt], acc[mt][nt], 0, 0, 0);
                    acc[mt][nt] = __builtin_amdgcn_mfma_f32_16x16x32_bf16(afl[mt], bf[nt], acc[mt][nt], 0, 0, 0);
                }
            }
        __syncthreads();
    }
    #pragma unroll
    for (int nt = 0; nt < 2; nt++) {
        int n = n0 + wn + nt * 16 + l15;
        float bs = bias[n];
        #pragma unroll
        for (int mt = 0; mt < 4; mt++) {
            int mloc = m0 + wm + mt * 16 + lk4;
            float4 v;
            float* vp = (float*)&v;
            #pragma unroll
            for (int r = 0; r < 4; r++) {
                float q = acc[mt][nt][r] + bs;
                if (LRELU) q = (q < 0.f) ? 0.1f * q : q;
                vp[r] = q;
            }
            *(float4*)&C[(size_t)n * M + mloc] = v;
        }
    }
}

// ---------------------------------------------------------------- amp = sqrt(re^2+im^2), layout -> [c][t][kf]
__global__ __launch_bounds__(128) void k_ampc(const float* __restrict__ F2C, float* __restrict__ ampb) {
    int bid = blockIdx.x;          // c*128 + t
    int kf = threadIdx.x;
    if (kf >= 65) return;
    int c = bid >> 7, t = bid & 127;
    size_t m = (size_t)c * 65 + kf;
    float re = F2C[(size_t)t * 16640 + m];
    float im = F2C[(size_t)(t + 128) * 16640 + m];
    ampb[(size_t)bid * 65 + kf] = sqrtf(re * re + im * im);
}

// ---------------------------------------------------------------- z = a*(cos a, sin a) -> stacked [t][(c,kf)] planes
__global__ __launch_bounds__(128) void k_zbuild(const float* __restrict__ A2, float* __restrict__ Z) {
    int bid = blockIdx.x;          // c*128 + t
    int kf = threadIdx.x;
    if (kf >= 65) return;
    int c = bid >> 7, t = bid & 127;
    float a = A2[(size_t)bid * 65 + kf];
    float s_, c_;
    sincosf(a, &s_, &c_);
    size_t m = (size_t)c * 65 + kf;
    Z[(size_t)t * 16640 + m] = a * c_;
    Z[2129920 + (size_t)t * 16640 + m] = a * s_;
}

// ---------------------------------------------------------------- h3s = W2c @ g1 + b2c  (3ch @128^2; g1 [128][16384])
__global__ __launch_bounds__(256) void k_h3s(const float* __restrict__ g1, const float* __restrict__ W2c,
                                             const float* __restrict__ b2c, float* __restrict__ h3s) {
    __shared__ float wa[384], bs[3];
    int tid = threadIdx.x;
    if (tid < 256) wa[tid] = W2c[tid];
    if (tid < 128) wa[256 + tid] = W2c[256 + tid];
    if (tid < 3) bs[tid] = b2c[tid];
    __syncthreads();
    int q = blockIdx.x * 256 + tid;   // [0,16384)
    float a0 = bs[0], a1 = bs[1], a2 = bs[2];
    #pragma unroll 4
    for (int c = 0; c < 128; c++) {
        float v = g1[(size_t)c * 16384 + q];
        a0 += wa[c] * v;
        a1 += wa[128 + c] * v;
        a2 += wa[256 + c] * v;
    }
    h3s[q] = a0; h3s[16384 + q] = a1; h3s[32768 + q] = a2;
}

// ---------------------------------------------------------------- channels-first bilinear x2 resize [C][H][H] -> [C][2H][2H]
__global__ __launch_bounds__(256) void k_resize2(const float* __restrict__ src, float* __restrict__ dst,
                                                 int C, int H) {
    int W2 = 2 * H;
    size_t idx = (size_t)blockIdx.x * 256 + threadIdx.x;
    size_t plane = (size_t)W2 * W2;
    if (idx >= (size_t)C * plane) return;
    int c = (int)(idx / plane);
    int rem = (int)(idx - (size_t)c * plane);
    int i = rem / W2, j = rem - i * W2;
    int ky = i >> 1, ylo, yhi; float wyl, wyh;
    if ((i & 1) == 0) { ylo = ky - 1; yhi = ky; wyl = .25f; wyh = .75f; if (ylo < 0) { ylo = 0; wyl = 0.f; wyh = 1.f; } }
    else              { ylo = ky; yhi = ky + 1; wyl = .75f; wyh = .25f; if (yhi > H - 1) { yhi = H - 1; wyh = 0.f; wyl = 1.f; } }
    int kx = j >> 1, xlo, xhi; float wxl, wxh;
    if ((j & 1) == 0) { xlo = kx - 1; xhi = kx; wxl = .25f; wxh = .75f; if (xlo < 0) { xlo = 0; wxl = 0.f; wxh = 1.f; } }
    else              { xlo = kx; xhi = kx + 1; wxl = .75f; wxh = .25f; if (xhi > H - 1) { xhi = H - 1; wxh = 0.f; wxl = 1.f; } }
    const float* p = src + (size_t)c * H * H;
    dst[idx] = wyl * (wxl * p[(size_t)ylo * H + xlo] + wxh * p[(size_t)ylo * H + xhi]) +
               wyh * (wxl * p[(size_t)yhi * H + xlo] + wxh * p[(size_t)yhi * H + xhi]);
}

// ---------------------------------------------------------------- final fused stage @512^2 (R3-verified)
__global__ __launch_bounds__(256) void k_final(const float* __restrict__ x,
                                               const float* __restrict__ dark, const int* __restrict__ gmax,
                                               const float* __restrict__ wcf1, const float* __restrict__ bcf1,
                                               const float* __restrict__ Wc, const float* __restrict__ bc,
                                               const float* __restrict__ g4, const float* __restrict__ h3,
                                               float* __restrict__ out) {
    __shared__ float dimt[32], w1[192], b1[64], wb[192], bcs[3];
    int tid = threadIdx.x;
    if (tid < 32) dimt[tid] = powf(10000.f, (float)(2 * (tid >> 1)) / 32.f);
    if (tid < 192) w1[tid] = wcf1[tid];
    if (tid < 64) b1[tid] = bcf1[tid];
    if (tid < 192) { int r = tid / 64, c = tid - (tid / 64) * 64; wb[tid] = Wc[r * 128 + 64 + c]; }
    if (tid < 3) bcs[tid] = bc[tid];
    __syncthreads();
    int p = blockIdx.x * 256 + tid;
    int i = p >> 9, j = p & 511;
    const float scale = 2.f * PI_F;
    float inv511 = scale / (511.f + 1e-6f);
    float xe = (float)j * inv511, ye = (float)i * inv511;
    float gm = __int_as_float(gmax[0]);
    float ze = dark[p] / (gm + 1e-6f) * scale;
    float x0 = x[p], x1 = x[p + NPIX], x2 = x[p + 2 * NPIX];

    int ky = i >> 1, ylo, yhi; float wyl, wyh;
    if ((i & 1) == 0) { ylo = ky - 1; yhi = ky; wyl = .25f; wyh = .75f; if (ylo < 0) { ylo = 0; wyl = 0.f; wyh = 1.f; } }
    else              { ylo = ky; yhi = ky + 1; wyl = .75f; wyh = .25f; if (yhi > 255) { yhi = 255; wyh = 0.f; wyl = 1.f; } }
    int kx = j >> 1, xlo, xhi; float wxl, wxh;
    if ((j & 1) == 0) { xlo = kx - 1; xhi = kx; wxl = .25f; wxh = .75f; if (xlo < 0) { xlo = 0; wxl = 0.f; wxh = 1.f; } }
    else              { xlo = kx; xhi = kx + 1; wxl = .75f; wxh = .25f; if (xhi > 255) { xhi = 255; wxh = 0.f; wxl = 1.f; } }
    int s00 = ylo * 256 + xlo, s01 = ylo * 256 + xhi, s10 = yhi * 256 + xlo, s11 = yhi * 256 + xhi;
    float w00 = wyl * wxl, w01 = wyl * wxh, w10 = wyh * wxl, w11 = wyh * wxh;

    float a0 = 0.f, a1 = 0.f, a2 = 0.f;
    #pragma unroll 1
    for (int c = 0; c < 64; c++) {
        float e = (c < 16) ? xe / dimt[c] : (c < 32) ? ye / dimt[c - 16] : ze / dimt[c - 32];
        float sn, cs;
        __sincosf(e, &sn, &cs);
        float pos = ((c & 1) == 0) ? sn : cs;
        float ape = pos + w1[c * 3] * x0 + w1[c * 3 + 1] * x1 + w1[c * 3 + 2] * x2 + b1[c];
        const float* gp = g4 + (size_t)c * 65536;
        float gv = w00 * gp[s00] + w01 * gp[s01] + w10 * gp[s10] + w11 * gp[s11];
        float s = gv * ape;
        a0 += wb[c] * s; a1 += wb[64 + c] * s; a2 += wb[128 + c] * s;
    }
    float f0 = w00 * h3[s00] + w01 * h3[s01] + w10 * h3[s10] + w11 * h3[s11];
    const float* h1 = h3 + 65536;
    float f1 = w00 * h1[s00] + w01 * h1[s01] + w10 * h1[s10] + w11 * h1[s11];
    const float* h2 = h3 + 131072;
    float f2 = w00 * h2[s00] + w01 * h2[s01] + w10 * h2[s10] + w11 * h2[s11];
    out[p]            = a0 + f0 + bcs[0] + x0;
    out[NPIX + p]     = a1 + f1 + bcs[1] + x1;
    out[2 * NPIX + p] = a2 + f2 + bcs[2] + x2;
}

// ================================================================ launcher
extern "C" void kernel_launch(void* const* d_in, const int* in_sizes, int n_in,
                              void* d_out, int out_size, void* d_ws, size_t ws_size,
                              hipStream_t stream) {
    const float* x      = (const float*)d_in[0];
    const float* w_cf1  = (const float*)d_in[1];  const float* b_cf1 = (const float*)d_in[2];
    const float* w_e1   = (const float*)d_in[3];  const float* b_e1  = (const float*)d_in[4];
    const float* w_e2   = (const float*)d_in[5];  const float* b_e2  = (const float*)d_in[6];
    const float* w_d1   = (const float*)d_in[7];  const float* b_d1  = (const float*)d_in[8];
    const float* w_d2   = (const float*)d_in[9];  const float* b_d2  = (const float*)d_in[10];
    // 11..14: pha branch is dead code in the reference
    const float* w_amp1 = (const float*)d_in[15]; const float* b_amp1 = (const float*)d_in[16];
    const float* w_amp2 = (const float*)d_in[17]; const float* b_amp2 = (const float*)d_in[18];
    const float* w_sp1  = (const float*)d_in[19]; const float* b_sp1  = (const float*)d_in[20];
    const float* w_sp2  = (const float*)d_in[21]; const float* b_sp2  = (const float*)d_in[22];
    const float* w_u1   = (const float*)d_in[23]; const float* b_u1   = (const float*)d_in[24];
    const float* w_u2   = (const float*)d_in[25]; const float* b_u2   = (const float*)d_in[26];
    const float* w_u3   = (const float*)d_in[27]; const float* b_u3   = (const float*)d_in[28];
    const float* w_u4   = (const float*)d_in[29]; const float* b_u4   = (const float*)d_in[30];
    const float* w_cf2  = (const float*)d_in[31]; const float* b_cf2  = (const float*)d_in[32];
    const float* w_cf3  = (const float*)d_in[33]; const float* b_cf3  = (const float*)d_in[34];
    float* out = (float*)d_out;

    char* ws = (char*)d_ws;
    constexpr size_t MiB = 1ull << 20;
    float*  dark   = (float*)(ws + 0 * MiB);
    float*  tmp    = (float*)(ws + 1 * MiB);
    int*    gmax   = (int*)  (ws + 2 * MiB);
    float*  Wc     = (float*)(ws + 2 * MiB + 1024);
    float*  bc     = (float*)(ws + 2 * MiB + 1024 + 1536);
    float*  W2c    = (float*)(ws + 2 * MiB + 4096);
    float*  b2c    = (float*)(ws + 2 * MiB + 4096 + 1536);
    float*  xf     = (float*)(ws + 3 * MiB);     // [3,67)
    float*  xd1    = (float*)(ws + 67 * MiB);    // [67,99)
    float*  xd2    = (float*)(ws + 99 * MiB);    // [99,115) live until sp1
    float*  F1C    = (float*)(ws + 115 * MiB);   // 32    [115,147)
    float*  F2C    = (float*)(ws + 147 * MiB);   // 16.25 [147,163.25)
    float*  ampb   = (float*)(ws + 164 * MiB);   // 8.125 [164,172.125)
    float*  A1     = (float*)(ws + 173 * MiB);   // 8.125 [173,181.125)
    float*  A2     = (float*)(ws + 182 * MiB);   // 8.125 [182,190.125)
    float*  Zbuf   = (float*)(ws + 115 * MiB);   // 16.25 (F1C dead after F2)
    float*  I1C    = (float*)(ws + 132 * MiB);   // [132,149)
    float*  I2C    = (float*)(ws + 149 * MiB);   // [149,165)
    float*  g1out  = (float*)(ws + 3 * MiB);     // 8 MiB, xf dead after d1
    float*  h3s    = (float*)(ws + 11 * MiB);    // 0.1875 [11,11.2)
    float*  h3     = (float*)(ws + 27 * MiB);    // 0.75  [27,27.75)
    float*  s1     = (float*)(ws + 31 * MiB);    // [31,47)
    float*  s2     = (float*)(ws + 47 * MiB);    // [47,63)
    float*  g3out  = (float*)(ws + 63 * MiB);    // [63,71) (xd1 dead)
    float*  g4out  = (float*)(ws + 71 * MiB);    // [71,87)
    float*  g4s    = (float*)(ws + 87 * MiB);    // 4 MiB [87,91)
    unsigned short* wb16 = (unsigned short*)(ws + 192 * MiB);  // [192,196)
    unsigned short* d1h = wb16 + 0,       * d1l = wb16 + 32768;
    unsigned short* d2h = wb16 + 65536,   * d2l = wb16 + 196608;
    unsigned short* a1h = wb16 + 327680,  * a1l = wb16 + 393216;
    unsigned short* a2h = wb16 + 458752,  * a2l = wb16 + 524288;
    unsigned short* s1h = wb16 + 589824;
    unsigned short* s2h = wb16 + 655360;
    unsigned short* u1h = wb16 + 720896;
    unsigned short* u3h = wb16 + 753664;
    unsigned short* u4h = wb16 + 1155072;  // 8192 shorts, ends 1163264 < 2M
    unsigned short* BfH = wb16 + 786432,  * BfL = wb16 + 819200;
    unsigned short* BfcH = wb16 + 851968, * BfcL = wb16 + 917504;
    unsigned short* BicH = wb16 + 983040, * BicL = wb16 + 1048576;
    unsigned short* BirH = wb16 + 1114112,* BirL = wb16 + 1134592;
    float* zbias = (float*)(ws + 195 * MiB + 512 * 1024);

    // 1) dark channel + gmax + composed weights + weight/B prep
    k_minc<<<1024, 256, 0, stream>>>(x, dark, gmax);
    k_minrow<<<1024, 256, 0, stream>>>(dark, tmp);
    k_mincol_max<<<1024, 256, 0, stream>>>(tmp, dark, gmax);
    k_wc<<<1, 128, 0, stream>>>(w_cf2, b_cf2, w_cf3, b_cf3, w_u2, b_u2, Wc, bc, W2c, b2c);
    k_prepw<<<128, 256, 0, stream>>>(w_d1, d1h, d1l, 128, 256, 6);
    k_prepw<<<512, 256, 0, stream>>>(w_d2, d2h, d2l, 256, 512, 7);
    k_prepw<<<256, 256, 0, stream>>>(w_amp1, a1h, a1l, 256, 256, 0);
    k_prepw<<<256, 256, 0, stream>>>(w_amp2, a2h, a2l, 256, 256, 0);
    k_prepw<<<256, 256, 0, stream>>>(w_sp1, s1h, nullptr, 256, 256, 0);
    k_prepw<<<256, 256, 0, stream>>>(w_sp2, s2h, nullptr, 256, 256, 0);
    k_prepw<<<128, 256, 0, stream>>>(w_u1, u1h, nullptr, 128, 256, 0);
    k_prepw<<<128, 256, 0, stream>>>(w_u3, u3h, nullptr, 128, 256, 0);
    k_prepw<<<32, 256, 0, stream>>>(w_u4, u4h, nullptr, 64, 128, 0);
    k_bfft<<<720, 256, 0, stream>>>(BfH, BfL, BfcH, BfcL, BicH, BicL, BirH, BirL, zbias);

    // 2) x_f channels-first
    k_ef<<<1024, 256, 0, stream>>>(x, w_e1, b_e1, w_e2, b_e2, xf);

    // 3) d1/d2 (MFMA split, s2d)
    k_mmcf<1, 1, 0><<<dim3(512, 2), 256, 0, stream>>>(xf, d1h, d1l, b_d1, xd1, 65536, 128, 256, 6, 8, 512);
    k_mmcf<1, 1, 0><<<dim3(128, 4), 256, 0, stream>>>(xd1, d2h, d2l, b_d2, xd2, 16384, 256, 512, 7, 7, 256);

    // 4) FFT section as MFMA GEMMs
    k_mmcf<3, 1, 0><<<dim3(256, 4), 256, 0, stream>>>(xd2, BfH, BfL, zbias, F1C, 32768, 256, 128, 0, 0, 0);
    k_mmcf<4, 1, 0><<<dim3(130, 4), 256, 0, stream>>>(F1C, BfcH, BfcL, zbias, F2C, 16640, 256, 256, 0, 0, 0);
    k_ampc<<<32768, 128, 0, stream>>>(F2C, ampb);
    k_mmcf<0, 1, 1><<<dim3(65, 4), 256, 0, stream>>>(ampb, a1h, a1l, b_amp1, A1, 8320, 256, 256, 0, 0, 0);
    k_mmcf<0, 1, 0><<<dim3(65, 4), 256, 0, stream>>>(A1, a2h, a2l, b_amp2, A2, 8320, 256, 256, 0, 0, 0);
    k_zbuild<<<32768, 128, 0, stream>>>(A2, Zbuf);
    k_mmcf<0, 1, 0><<<dim3(130, 4), 256, 0, stream>>>(Zbuf, BicH, BicL, zbias, I1C, 16640, 256, 256, 0, 0, 0);
    k_mmcf<5, 1, 0><<<dim3(256, 2), 256, 0, stream>>>(I1C, BirH, BirL, zbias, I2C, 32768, 128, 160, 0, 0, 0);

    // 5) four path: u1 (MFMA) ; h3s = (Wc_a@u2) @ g1 @128^2 ; resize 3ch -> h3@256^2
    k_mmcf<6, 0, 0><<<dim3(128, 2), 256, 0, stream>>>(I2C, u1h, nullptr, b_u1, g1out, 16384, 128, 256, 0, 0, 0);
    k_h3s<<<64, 256, 0, stream>>>(g1out, W2c, b2c, h3s);
    k_resize2<<<768, 256, 0, stream>>>(h3s, h3, 3, 128);

    // 6) spat path: sp1, sp2, u3 (MFMA) @128^2 ; u4 (MFMA) @128^2 ; resize 64ch -> g4out@256^2
    k_mmcf<0, 0, 1><<<dim3(128, 4), 256, 0, stream>>>(xd2, s1h, nullptr, b_sp1, s1, 16384, 256, 256, 0, 0, 0);
    k_mmcf<0, 0, 0><<<dim3(128, 4), 256, 0, stream>>>(s1, s2h, nullptr, b_sp2, s2, 16384, 256, 256, 0, 0, 0);
    k_mmcf<0, 0, 0><<<dim3(128, 2), 256, 0, stream>>>(s2, u3h, nullptr, b_u3, g3out, 16384, 128, 256, 0, 0, 0);
    k_mmcf<0, 0, 0><<<dim3(128, 1), 256, 0, stream>>>(g3out, u4h, nullptr, b_u4, g4s, 16384, 64, 128, 0, 0, 0);
    k_resize2<<<16384, 256, 0, stream>>>(g4s, g4out, 64, 128);

    // 7) final fused stage
    k_final<<<1024, 256, 0, stream>>>(x, dark, gmax, w_cf1, b_cf1, Wc, bc, g4out, h3, out);
}